// Round 10
// baseline (364.163 us; speedup 1.0000x reference)
//
#include <hip/hip_runtime.h>
#include <hip/hip_bf16.h>
#include <math.h>

// Problem constants
#define BB 16
#define NP 150
#define NN 151          // N = Np + 1
#define DD 256
#define HH 8
#define HD 32
#define FFN_ 1024
#define PE_LEN 20200
#define ROWS (BB*NN)    // 2416
#define MPAD 2432       // ROWS padded to 32
#define PE_PAD 20224    // PE_LEN padded to 32
#define SQS 160         // Sqk padded row (151->160)

// r16: pekv 128x32/wave (317us). r17: skinny Nc=256 + pekv/qkv0 merge
// (304us). r18/r19/r20: reverted experiments (prefetch depth, nt stores,
// wide-skinny). r21: score distribution s = q·Kx + q·PEK[tj] — gemm_sqk
// (batched MFMA) precomputes Sqk = Q@Kx^T; attn L0 Phase A = PE-gather dot
// only, L1 Phase A = none (302.8us, absmax 0.0742; all kernels < 44us).
// r22: dispatch/roundtrip reduction — out-proj + residual + LN are
// ROW-LOCAL after attn's cross-group reduce, so fuse them into the attn
// block: y-row packed to bf16 pairs in LDS (preserves yb operand rounding),
// per-thread 256-dot vs streamed out_w row (dot2, 4 accumulators), then
// r16(r16(dot)+r16(bias)), residual add, LN. Removes 2 skinny + 2 add_ln
// dispatches and the yb/y2 roundtrips (~10MB). Numerics: only f32 dot
// regrouping (MFMA-tree -> dot2 chain), same class as prior rounds.
// Index semantics: pe0 idx = 10100; rel-bucket clips -> 100 / 20100.

typedef __attribute__((ext_vector_type(8))) short short8;   // 8 bf16 = 4 VGPR
typedef __attribute__((ext_vector_type(4))) float f32x4;
typedef __attribute__((ext_vector_type(4))) unsigned u32x4; // 4 dwords

#if defined(__has_builtin)
#if __has_builtin(__builtin_amdgcn_fdot2_f32_bf16)
#define HAVE_DOT2 1
#endif
#endif
#ifndef HAVE_DOT2
#define HAVE_DOT2 0
#endif

__device__ __forceinline__ float r16(float x) {
    return __bfloat162float(__float2bfloat16(x));   // RNE bf16 grid
}
__device__ __forceinline__ float us2f(unsigned short u) {
    return __uint_as_float((unsigned)u << 16);      // bf16 bits -> f32
}
__device__ __forceinline__ float lo2f(unsigned x) {
    return __uint_as_float(x << 16);                // low bf16 of dword
}
__device__ __forceinline__ float hi2f(unsigned x) {
    return __uint_as_float(x & 0xFFFF0000u);        // high bf16 of dword
}
__device__ __forceinline__ unsigned cvtpk(float lo, float hi) {
    unsigned r;                                     // D.lo=bf16(lo) D.hi=bf16(hi), RNE
    asm("v_cvt_pk_bf16_f32 %0, %1, %2" : "=v"(r) : "v"(lo), "v"(hi));
    return r;
}
#if HAVE_DOT2
typedef __attribute__((ext_vector_type(2))) __bf16 bf16x2;
__device__ __forceinline__ float dot2bf(unsigned a, unsigned b, float acc) {
    bf16x2 av = __builtin_bit_cast(bf16x2, a);
    bf16x2 bv = __builtin_bit_cast(bf16x2, b);
    return __builtin_amdgcn_fdot2_f32_bf16(av, bv, acc, false);
}
#endif

// ---------------------------------------------------------------------------
// build_x (+ fused weight packs on trailing blocks).
// ---------------------------------------------------------------------------
#define PACK_BLOCKS 1024
__global__ __launch_bounds__(256) void buildpack_kernel(
    const float* __restrict__ spectra, const float* __restrict__ latent,
    const float* __restrict__ int_w, const float* __restrict__ pe,
    float* __restrict__ x, __hip_bfloat16* __restrict__ xb,
    __hip_bfloat16* __restrict__ xqb,
    float* __restrict__ masses, float* __restrict__ maskf,
    const float* __restrict__ in_w,  __hip_bfloat16* __restrict__ inw_p,
    const float* __restrict__ out_w, __hip_bfloat16* __restrict__ outw_p,
    const float* __restrict__ l1_w,  __hip_bfloat16* __restrict__ l1w_p,
    const float* __restrict__ l2_w,  __hip_bfloat16* __restrict__ l2w_p,
    __hip_bfloat16* __restrict__ pe_p)
{
    int tid = threadIdx.x;
    if (blockIdx.x < ROWS) {
        int bn = blockIdx.x;            // b*NN + n
        int b = bn / NN, n = bn % NN;
        float val;
        if (n == 0) {
            val = latent[tid];
            if (tid == 0) { masses[bn] = 0.0f; maskf[bn] = 0.0f; }
        } else {
            float mz = spectra[(b*NP + n - 1)*2 + 0];
            float it = spectra[(b*NP + n - 1)*2 + 1];
            int i = (tid < 128) ? tid : tid - 128;
            const double base_d = 0.001 / (2.0 * 3.141592653589793);
            double term_d = base_d * pow(1.0e7, (double)i / 127.0);
            float tf = (float)term_d;                   // .astype(np.float32)
            double arg = (double)mz / (double)tf;
            double sv = (tid < 128) ? sin(arg) : cos(arg);
            val = (float)sv + it * int_w[tid];
            if (tid == 0) {
                masses[bn] = mz;
                maskf[bn] = ((mz + it) == 0.0f) ? 1.0f : 0.0f;
            }
        }
        x[bn*DD + tid] = val;
        xb[bn*DD + tid] = __float2bfloat16(val);
        xqb[bn*DD + tid] = __float2bfloat16(val + pe[10100*DD + tid]);
    } else {
        long long base = (long long)(blockIdx.x - ROWS) * 256 + tid;
        const long long stride = (long long)PACK_BLOCKS * 256;
        for (long long i = base; i < (long long)PE_PAD*DD; i += stride)
            pe_p[i] = __float2bfloat16(i < (long long)PE_LEN*DD ? pe[i] : 0.0f);
        for (long long i = base; i < 2LL*768*DD; i += stride)
            inw_p[i] = __float2bfloat16(in_w[i]);
        for (long long i = base; i < 2LL*DD*DD; i += stride)
            outw_p[i] = __float2bfloat16(out_w[i]);
        for (long long i = base; i < 2LL*FFN_*DD; i += stride)
            l1w_p[i] = __float2bfloat16(l1_w[i]);
        for (long long i = base; i < 2LL*DD*FFN_; i += stride)
            l2w_p[i] = __float2bfloat16(l2_w[i]);
    }
}

// ---------------------------------------------------------------------------
// MFMA GEMM: C[M,Nc] = A(bf16) @ W(bf16)^T, f32 acc, epilogue
// r16(r16(acc)+r16(bias)). One wave per 32x32 tile. (wide-Nc ROWS GEMMs.)
// ---------------------------------------------------------------------------
template<typename CT>
__global__ __launch_bounds__(256) void gemm_mfma(
    const __hip_bfloat16* __restrict__ A, const __hip_bfloat16* __restrict__ W,
    const float* __restrict__ bias, CT* __restrict__ C,
    int M, int Nc, int K, int ldc, int relu)
{
    int wave = threadIdx.x >> 6;
    int lane = threadIdx.x & 63;
    int NT = Nc >> 5;
    int MT = (M + 31) >> 5;
    int id = blockIdx.x * 4 + wave;
    if (id >= MT * NT) return;
    int mt = id / NT, nt = id % NT;
    int m0 = mt * 32, n0 = nt * 32;
    int rl = lane & 15, q8 = (lane >> 4) * 8;

    const short8* Ap0 = (const short8*)(A + (size_t)(m0 + rl)*K + q8);
    const short8* Ap1 = (const short8*)(A + (size_t)(m0 + 16 + rl)*K + q8);
    const short8* Wp0 = (const short8*)(W + (size_t)(n0 + rl)*K + q8);
    const short8* Wp1 = (const short8*)(W + (size_t)(n0 + 16 + rl)*K + q8);

    f32x4 acc00 = {0,0,0,0}, acc01 = {0,0,0,0};
    f32x4 acc10 = {0,0,0,0}, acc11 = {0,0,0,0};
    int steps = K >> 5;
    for (int s = 0; s < steps; ++s) {
        short8 a0 = Ap0[s*4];
        short8 a1 = Ap1[s*4];
        short8 b0 = Wp0[s*4];
        short8 b1 = Wp1[s*4];
        acc00 = __builtin_amdgcn_mfma_f32_16x16x32_bf16(a0, b0, acc00, 0, 0, 0);
        acc01 = __builtin_amdgcn_mfma_f32_16x16x32_bf16(a0, b1, acc01, 0, 0, 0);
        acc10 = __builtin_amdgcn_mfma_f32_16x16x32_bf16(a1, b0, acc10, 0, 0, 0);
        acc11 = __builtin_amdgcn_mfma_f32_16x16x32_bf16(a1, b1, acc11, 0, 0, 0);
    }

    int rbase = (lane >> 4) * 4;
    #pragma unroll
    for (int sm = 0; sm < 2; ++sm) {
        #pragma unroll
        for (int sn = 0; sn < 2; ++sn) {
            f32x4 a = (sm == 0) ? (sn == 0 ? acc00 : acc01)
                                : (sn == 0 ? acc10 : acc11);
            int gc = n0 + sn*16 + rl;
            float bv = bias ? r16(bias[gc]) : 0.0f;
            #pragma unroll
            for (int rg = 0; rg < 4; ++rg) {
                int gr = m0 + sm*16 + rbase + rg;
                if (gr < M) {
                    float val = r16(a[rg]);
                    if (bias) val = r16(val + bv);
                    if (relu) val = fmaxf(val, 0.0f);
                    C[(size_t)gr*ldc + gc] = (CT)val;
                }
            }
        }
    }
}

// ---------------------------------------------------------------------------
// Skinny GEMM for Nc=256 (FFN-down): one 16x32 tile per BLOCK, K split
// across the 4 waves, LDS partial reduce, distributed epilogue.
// ---------------------------------------------------------------------------
template<int K>
__global__ __launch_bounds__(256) void gemm_skinny(
    const __hip_bfloat16* __restrict__ A, const __hip_bfloat16* __restrict__ W,
    const float* __restrict__ bias, float* __restrict__ C,
    int M, int Nc, int ldc)
{
    int NT = Nc >> 5;
    int id = blockIdx.x;
    int mt = id / NT, nt = id % NT;
    int m0 = mt * 16, n0 = nt * 32;
    int wave = threadIdx.x >> 6;
    int lane = threadIdx.x & 63;
    int rl = lane & 15, q8 = (lane >> 4) * 8;
    const int K4 = K >> 2;              // K slice per wave
    int k0 = wave * K4;

    const short8* Ap  = (const short8*)(A + (size_t)(m0 + rl)*K + k0 + q8);
    const short8* Wp0 = (const short8*)(W + (size_t)(n0 + rl)*K + k0 + q8);
    const short8* Wp1 = (const short8*)(W + (size_t)(n0 + 16 + rl)*K + k0 + q8);

    f32x4 acc0 = {0,0,0,0}, acc1 = {0,0,0,0};
    #pragma unroll
    for (int s = 0; s < K4/32; ++s) {
        short8 a  = Ap[s*4];
        short8 b0 = Wp0[s*4];
        short8 b1 = Wp1[s*4];
        acc0 = __builtin_amdgcn_mfma_f32_16x16x32_bf16(a, b0, acc0, 0, 0, 0);
        acc1 = __builtin_amdgcn_mfma_f32_16x16x32_bf16(a, b1, acc1, 0, 0, 0);
    }

    __shared__ float red[4][8][65];     // [wave][slot][lane] pad->no conflicts
    #pragma unroll
    for (int rg = 0; rg < 4; ++rg) {
        red[wave][rg][lane]   = acc0[rg];
        red[wave][4+rg][lane] = acc1[rg];
    }
    __syncthreads();

    #pragma unroll
    for (int t = 0; t < 2; ++t) {
        int sl = wave*2 + t;
        float s = red[0][sl][lane] + red[1][sl][lane]
                + red[2][sl][lane] + red[3][sl][lane];
        int rg = sl & 3, sn = sl >> 2;
        int gr = m0 + (lane >> 4)*4 + rg;
        int gc = n0 + sn*16 + rl;
        float val = r16(s);
        val = r16(val + r16(bias[gc]));
        if (gr < M) C[(size_t)gr*ldc + gc] = val;
    }
}

// ---------------------------------------------------------------------------
// Batched score GEMM: Sqk[b][h][i][j] = sum_d Q[b,i,h*32+d] * K[b,j,h*32+d],
// f32, unscaled, unmasked. One 16x16 (i x j) tile per wave, K=32 = 1 MFMA.
// ---------------------------------------------------------------------------
template<int QS, int KS>
__global__ __launch_bounds__(256) void gemm_sqk(
    const __hip_bfloat16* __restrict__ Q, const __hip_bfloat16* __restrict__ Kp,
    float* __restrict__ S)
{
    int wave = threadIdx.x >> 6;
    int lane = threadIdx.x & 63;
    int id = blockIdx.x * 4 + wave;         // b(16) x h(8) x it(10) x jt(10)
    if (id >= 16*8*100) return;
    int jt = id % 10, it = (id / 10) % 10;
    int h = (id / 100) & 7, b = id / 800;
    int i0 = it * 16, j0 = jt * 16;
    int rl = lane & 15, q8 = (lane >> 4) * 8;

    short8 a  = *(const short8*)(Q  + (size_t)(b*NN + i0 + rl)*QS + h*32 + q8);
    short8 kb = *(const short8*)(Kp + (size_t)(b*NN + j0 + rl)*KS + h*32 + q8);
    f32x4 acc = {0,0,0,0};
    acc = __builtin_amdgcn_mfma_f32_16x16x32_bf16(a, kb, acc, 0, 0, 0);

    float* Sb = S + ((size_t)(b*8 + h))*SQS*SQS;
    int rbase = (lane >> 4) * 4;
    #pragma unroll
    for (int rg = 0; rg < 4; ++rg) {
        int ii = i0 + rbase + rg, jj = j0 + rl;
        if (ii < NN && jj < NN)
            Sb[(size_t)ii*SQS + jj] = acc[rg];
    }
}

// ---------------------------------------------------------------------------
// Merged pekv GEMM + L0 QKV projection (independent, both read weight packs).
// ---------------------------------------------------------------------------
#define PEKV_BLK 632u   // ceil(158*16 tiles / 4 waves)
#define QKV0_BLK 456u   // ceil(76*24 tiles / 4 waves)

__device__ __forceinline__ void pekv_body(
    unsigned bid, int wave, int lane,
    const __hip_bfloat16* __restrict__ A, const __hip_bfloat16* __restrict__ W,
    __hip_bfloat16* __restrict__ C)
{
    const int K = 256, Nc = 512, ldc = 512, M = PE_LEN;
    int NT = Nc >> 5;
    int MT4 = (M + 127) >> 7;
    int id = bid * 4 + wave;
    if (id >= MT4 * NT) return;
    int mt = id / NT, nt = id % NT;
    int m0 = mt * 128, n0 = nt * 32;
    int rl = lane & 15, q8 = (lane >> 4) * 8;

    const short8* Ab  = (const short8*)(A + (size_t)(m0 + rl)*K + q8);
    const short8* Wp0 = (const short8*)(W + (size_t)(n0 + rl)*K + q8);
    const short8* Wp1 = (const short8*)(W + (size_t)(n0 + 16 + rl)*K + q8);
    const int rstep = K >> 3;                  // short8 units per row

    f32x4 acc[4][2][2] = {};
    for (int s = 0; s < 8; ++s) {              // K/32 = 8
        short8 b0 = Wp0[s*4];
        short8 b1 = Wp1[s*4];
        short8 a[4][2];
        #pragma unroll
        for (int t = 0; t < 4; ++t) {
            a[t][0] = Ab[(size_t)(t*32)*rstep + s*4];
            a[t][1] = Ab[(size_t)(t*32+16)*rstep + s*4];
        }
        #pragma unroll
        for (int t = 0; t < 4; ++t) {
            acc[t][0][0] = __builtin_amdgcn_mfma_f32_16x16x32_bf16(a[t][0], b0, acc[t][0][0], 0, 0, 0);
            acc[t][0][1] = __builtin_amdgcn_mfma_f32_16x16x32_bf16(a[t][0], b1, acc[t][0][1], 0, 0, 0);
            acc[t][1][0] = __builtin_amdgcn_mfma_f32_16x16x32_bf16(a[t][1], b0, acc[t][1][0], 0, 0, 0);
            acc[t][1][1] = __builtin_amdgcn_mfma_f32_16x16x32_bf16(a[t][1], b1, acc[t][1][1], 0, 0, 0);
        }
    }

    int rbase = (lane >> 4) * 4;
    #pragma unroll
    for (int t = 0; t < 4; ++t) {
        #pragma unroll
        for (int sm = 0; sm < 2; ++sm) {
            #pragma unroll
            for (int sn = 0; sn < 2; ++sn) {
                f32x4 a = acc[t][sm][sn];
                int gc = n0 + sn*16 + rl;
                #pragma unroll
                for (int rg = 0; rg < 4; ++rg) {
                    int gr = m0 + t*32 + sm*16 + rbase + rg;
                    if (gr < M)
                        C[(size_t)gr*ldc + gc] = (__hip_bfloat16)r16(a[rg]);
                }
            }
        }
    }
}

__device__ __forceinline__ void qkv0_body(
    unsigned bid, int wave, int lane,
    const __hip_bfloat16* __restrict__ xqb, const __hip_bfloat16* __restrict__ xb,
    const __hip_bfloat16* __restrict__ inw_p, const float* __restrict__ in_b,
    __hip_bfloat16* __restrict__ qb, __hip_bfloat16* __restrict__ kvb, int M)
{
    int MT = (M + 31) >> 5;
    int id = bid * 4 + wave;
    if (id >= MT * 24) return;
    int mt = id / 24, ntt = id % 24;
    bool isQ = (ntt < 8);
    const __hip_bfloat16* A = isQ ? xqb : xb;
    const __hip_bfloat16* W = inw_p + (isQ ? (size_t)ntt*32*DD
                                           : (size_t)(256 + (ntt-8)*32)*DD);
    const float* bias = in_b + (isQ ? ntt*32 : 256 + (ntt-8)*32);
    __hip_bfloat16* C = isQ ? qb : kvb;
    int ldc = isQ ? 256 : 512;
    int cbase = isQ ? ntt*32 : (ntt-8)*32;
    int m0 = mt * 32;
    int rl = lane & 15, q8 = (lane >> 4) * 8;
    const int K = DD;

    const short8* Ap0 = (const short8*)(A + (size_t)(m0 + rl)*K + q8);
    const short8* Ap1 = (const short8*)(A + (size_t)(m0 + 16 + rl)*K + q8);
    const short8* Wp0 = (const short8*)(W + (size_t)(rl)*K + q8);
    const short8* Wp1 = (const short8*)(W + (size_t)(16 + rl)*K + q8);

    f32x4 acc00 = {0,0,0,0}, acc01 = {0,0,0,0};
    f32x4 acc10 = {0,0,0,0}, acc11 = {0,0,0,0};
    for (int s = 0; s < K/32; ++s) {
        short8 a0 = Ap0[s*4];
        short8 a1 = Ap1[s*4];
        short8 b0 = Wp0[s*4];
        short8 b1 = Wp1[s*4];
        acc00 = __builtin_amdgcn_mfma_f32_16x16x32_bf16(a0, b0, acc00, 0, 0, 0);
        acc01 = __builtin_amdgcn_mfma_f32_16x16x32_bf16(a0, b1, acc01, 0, 0, 0);
        acc10 = __builtin_amdgcn_mfma_f32_16x16x32_bf16(a1, b0, acc10, 0, 0, 0);
        acc11 = __builtin_amdgcn_mfma_f32_16x16x32_bf16(a1, b1, acc11, 0, 0, 0);
    }

    int rbase = (lane >> 4) * 4;
    #pragma unroll
    for (int sm = 0; sm < 2; ++sm) {
        #pragma unroll
        for (int sn = 0; sn < 2; ++sn) {
            f32x4 a = (sm == 0) ? (sn == 0 ? acc00 : acc01)
                                : (sn == 0 ? acc10 : acc11);
            int gc = cbase + sn*16 + rl;
            float bv = r16(bias[sn*16 + rl]);
            #pragma unroll
            for (int rg = 0; rg < 4; ++rg) {
                int gr = m0 + sm*16 + rbase + rg;
                if (gr < M) {
                    float val = r16(a[rg]);
                    val = r16(val + bv);
                    C[(size_t)gr*ldc + gc] = (__hip_bfloat16)val;
                }
            }
        }
    }
}

__global__ __launch_bounds__(256) void pekv_qkv0_kernel(
    const __hip_bfloat16* __restrict__ pe_p, const __hip_bfloat16* __restrict__ wkv0,
    __hip_bfloat16* __restrict__ pekv,
    const __hip_bfloat16* __restrict__ xqb, const __hip_bfloat16* __restrict__ xb,
    const __hip_bfloat16* __restrict__ inw_p, const float* __restrict__ in_b,
    __hip_bfloat16* __restrict__ qb, __hip_bfloat16* __restrict__ kvb)
{
    int wave = threadIdx.x >> 6;
    int lane = threadIdx.x & 63;
    if (blockIdx.x < PEKV_BLK)
        pekv_body(blockIdx.x, wave, lane, pe_p, wkv0, pekv);
    else
        qkv0_body(blockIdx.x - PEKV_BLK, wave, lane, xqb, xb, inw_p, in_b,
                  qb, kvb, ROWS);
}

// ---------------------------------------------------------------------------
// Fused attention + out-proj + residual + layernorm. One block per (b,i),
// b = blk&15 (XCD locality). Thread (g = tid>>5, c = tid&31).
// Scores: Sqk preload; USE_PE adds PE-gather dot (Phase A). Phase B as r21.
// Epilogue (r22): y row -> bf16 pairs in LDS (= old yb rounding) ->
// per-thread 256-dot vs streamed out_w row -> r16(r16(dot)+r16(bias)) ->
// residual add vs xres -> LN -> write xout/xbout. No yb/y2 roundtrip.
// ---------------------------------------------------------------------------
template<bool USE_PE, int QS, int VS>
__global__ __launch_bounds__(256) void attn_kernel(
    const __hip_bfloat16* __restrict__ qp,
    const __hip_bfloat16* __restrict__ vp,
    const __hip_bfloat16* __restrict__ pekv,
    const float* __restrict__ sqk,
    const float* __restrict__ masses, const float* __restrict__ maskf,
    const __hip_bfloat16* __restrict__ outw, const float* __restrict__ outb,
    const float* __restrict__ xres,
    const float* __restrict__ lng, const float* __restrict__ lnb,
    float* __restrict__ xout, __hip_bfloat16* __restrict__ xbout)
{
    int b = blockIdx.x & 15;        // XCD-locality swizzle (pure permutation)
    int i = blockIdx.x >> 4;
    int tid = threadIdx.x;
    int c = tid & 31;               // 8-column chunk index
    int g = tid >> 5;               // row-residue class
    int h = c >> 2;                 // head owning columns c*8..c*8+7
    const float scale = 0.17677669529663687f;   // 1/sqrt(32)

    __shared__ float sc[HH][152];
    __shared__ float msh[152];
    __shared__ int   tj[152];
    __shared__ __align__(16) float part[8][264];
    __shared__ float yrow[256];
    __shared__ unsigned ypk[128];
    __shared__ float red2[4];

    if (tid < NN) {
        float mval = maskf[b*NN + tid];
        msh[tid] = mval;
        if (USE_PE) {
            double m = (double)masses[b*NN + tid] - (double)masses[b*NN + i];
            m = fmin(fmax(m, -100.0), 100.0);
            tj[tid] = (int)(((m + 1.0) + 100.0) / 0.01);  // f64: clips 100/20100
        }
        // preload Sqk rows (coalesced in j)
        const float* Sb = sqk + ((size_t)(b*8))*SQS*SQS + (size_t)i*SQS + tid;
        if (USE_PE) {
            #pragma unroll
            for (int hh = 0; hh < 8; ++hh)
                sc[hh][tid] = Sb[(size_t)hh*SQS*SQS];     // raw; PE+scale+mask in Phase A
        } else {
            #pragma unroll
            for (int hh = 0; hh < 8; ++hh) {
                float s = Sb[(size_t)hh*SQS*SQS] * scale;
                sc[hh][tid] = (mval != 0.0f) ? -1e9f : s;
            }
        }
    }

    // preload Q chunk (only needed for the PE dot)
    unsigned qw[4];
#if !HAVE_DOT2
    float qf[8];
#endif
    if (USE_PE) {
        const u32x4 q4 = *(const u32x4*)((const unsigned short*)qp
                            + (size_t)(b*NN + i)*QS + c*8);
        qw[0] = q4[0]; qw[1] = q4[1]; qw[2] = q4[2]; qw[3] = q4[3];
#if !HAVE_DOT2
        #pragma unroll
        for (int w = 0; w < 4; ++w) { qf[2*w] = lo2f(qw[w]); qf[2*w+1] = hi2f(qw[w]); }
#endif
    }
    __syncthreads();

    const unsigned short* vbase = (const unsigned short*)vp + (size_t)(b*NN)*VS + c*8;
    const unsigned short* pkb = (const unsigned short*)pekv + c*8;        // PEK col
    const unsigned short* pvb = (const unsigned short*)pekv + 256 + c*8;  // PEV col

    // ---- Phase A (USE_PE only): PE-gather dot added to preloaded Sqk ----
    if (USE_PE) {
        int j = g;
        u32x4 pcur = *(const u32x4*)(pkb + (size_t)tj[j]*512);
        for (int p = 0; p < 19; ++p) {
            int jn = j + 8;
            bool more = (jn < NN);
            u32x4 pn;
            if (more) pn = *(const u32x4*)(pkb + (size_t)tj[jn]*512);
            float acc = 0.0f;
#if HAVE_DOT2
            #pragma unroll
            for (int w = 0; w < 4; ++w) acc = dot2bf(qw[w], pcur[w], acc);
#else
            #pragma unroll
            for (int w = 0; w < 4; ++w) {
                acc = fmaf(qf[2*w],   lo2f(pcur[w]), acc);
                acc = fmaf(qf[2*w+1], hi2f(pcur[w]), acc);
            }
#endif
            acc += __shfl_xor(acc, 1);
            acc += __shfl_xor(acc, 2);
            if ((c & 3) == 0) {
                float s = (sc[h][j] + acc) * scale;
                if (msh[j] != 0.0f) s = -1e9f;
                sc[h][j] = s;
            }
            if (!more) break;
            j = jn; pcur = pn;
        }
        __syncthreads();
    }

    // ---- softmax per head, f32, within 32-lane group (head = g) ----
    {
        int lane = tid & 31;
        int hh = g;
        float mx = -INFINITY;
        for (int j = lane; j < NN; j += 32) mx = fmaxf(mx, sc[hh][j]);
        #pragma unroll
        for (int off = 16; off; off >>= 1) mx = fmaxf(mx, __shfl_xor(mx, off, 32));
        float sum = 0.0f;
        for (int j = lane; j < NN; j += 32) {
            float e = expf(sc[hh][j] - mx);
            sc[hh][j] = e;
            sum += e;
        }
        #pragma unroll
        for (int off = 16; off; off >>= 1) sum += __shfl_xor(sum, off, 32);
        float inv = 1.0f / sum;
        for (int j = lane; j < NN; j += 32) sc[hh][j] = r16(sc[hh][j] * inv); // bf16(a)
    }
    __syncthreads();

    // ---- Phase B: partial y over row class, then cross-group reduce ----
    {
        float ya[8];
        #pragma unroll
        for (int u = 0; u < 8; ++u) ya[u] = 0.0f;

#if HAVE_DOT2
        // rows paired (jA = g+16t, jB = jA+8), t = 0..8; tail row g+144 if valid
        u32x4 vA = *(const u32x4*)(vbase + (size_t)g*VS);
        u32x4 vB = *(const u32x4*)(vbase + (size_t)(g+8)*VS);
        u32x4 pA, pB;
        if (USE_PE) {
            pA = *(const u32x4*)(pvb + (size_t)tj[g]*512);
            pB = *(const u32x4*)(pvb + (size_t)tj[g+8]*512);
        }
        for (int t = 0; t < 9; ++t) {
            int jA = g + t*16, jB = jA + 8;
            u32x4 nvA, nvB, npA, npB;
            if (t < 8) {
                int nA = jA + 16, nB = jB + 16;
                nvA = *(const u32x4*)(vbase + (size_t)nA*VS);
                nvB = *(const u32x4*)(vbase + (size_t)nB*VS);
                if (USE_PE) {
                    npA = *(const u32x4*)(pvb + (size_t)tj[nA]*512);
                    npB = *(const u32x4*)(pvb + (size_t)tj[nB]*512);
                }
            }
            unsigned apair = cvtpk(sc[h][jA], sc[h][jB]);   // lo=aA hi=aB
            #pragma unroll
            for (int w = 0; w < 4; ++w) {
                unsigned lopair, hipair;
                if (USE_PE) {
                    float sA0 = lo2f(vA[w]) + lo2f(pA[w]);
                    float sA1 = hi2f(vA[w]) + hi2f(pA[w]);
                    float sB0 = lo2f(vB[w]) + lo2f(pB[w]);
                    float sB1 = hi2f(vB[w]) + hi2f(pB[w]);
                    lopair = cvtpk(sA0, sB0);
                    hipair = cvtpk(sA1, sB1);
                } else {
                    lopair = __builtin_amdgcn_perm(vB[w], vA[w], 0x05040100u);
                    hipair = __builtin_amdgcn_perm(vB[w], vA[w], 0x07060302u);
                }
                ya[2*w]   = dot2bf(apair, lopair, ya[2*w]);
                ya[2*w+1] = dot2bf(apair, hipair, ya[2*w+1]);
            }
            if (t < 8) {
                vA = nvA; vB = nvB;
                if (USE_PE) { pA = npA; pB = npB; }
            }
        }
        if (g + 144 < NN) {                 // tail row (g < 7)
            int jT = g + 144;
            u32x4 v = *(const u32x4*)(vbase + (size_t)jT*VS);
            u32x4 pq;
            if (USE_PE) pq = *(const u32x4*)(pvb + (size_t)tj[jT]*512);
            float aT = sc[h][jT];
            #pragma unroll
            for (int w = 0; w < 4; ++w) {
                float v0 = lo2f(v[w]), v1 = hi2f(v[w]);
                if (USE_PE) {
                    unsigned pk2 = cvtpk(v0 + lo2f(pq[w]), v1 + hi2f(pq[w]));
                    v0 = lo2f(pk2); v1 = hi2f(pk2);
                }
                ya[2*w]   = fmaf(aT, v0, ya[2*w]);
                ya[2*w+1] = fmaf(aT, v1, ya[2*w+1]);
            }
        }
#else
        int j = g;
        u32x4 vcur = *(const u32x4*)(vbase + (size_t)j*VS);
        u32x4 pcur;
        if (USE_PE) pcur = *(const u32x4*)(pvb + (size_t)tj[j]*512);
        float acur = sc[h][j];
        for (int p = 0; p < 19; ++p) {
            int jn = j + 8;
            bool more = (jn < NN);
            u32x4 vn, pn;
            float an = 0.0f;
            if (more) {
                vn = *(const u32x4*)(vbase + (size_t)jn*VS);
                if (USE_PE) pn = *(const u32x4*)(pvb + (size_t)tj[jn]*512);
                an = sc[h][jn];
            }
            #pragma unroll
            for (int w = 0; w < 4; ++w) {
                float v0 = lo2f(vcur[w]), v1 = hi2f(vcur[w]);
                if (USE_PE) {
                    v0 = r16(v0 + lo2f(pcur[w]));
                    v1 = r16(v1 + hi2f(pcur[w]));
                }
                ya[2*w]   = fmaf(acur, v0, ya[2*w]);
                ya[2*w+1] = fmaf(acur, v1, ya[2*w+1]);
            }
            if (!more) break;
            j = jn; vcur = vn; acur = an;
            if (USE_PE) pcur = pn;
        }
#endif
        f32x4* pp = (f32x4*)&part[g][c*8];
        pp[0] = f32x4{ya[0], ya[1], ya[2], ya[3]};
        pp[1] = f32x4{ya[4], ya[5], ya[6], ya[7]};
    }
    __syncthreads();

    // ---- fused out-proj + residual + layernorm (row-local) ----
    {
        float s = part[0][tid];
        #pragma unroll
        for (int g2 = 1; g2 < 8; ++g2) s += part[g2][tid];
        yrow[tid] = s;
    }
    __syncthreads();
    if (tid < 128) ypk[tid] = cvtpk(yrow[2*tid], yrow[2*tid + 1]);  // bf16 y operand
    __syncthreads();
    {
        const u32x4* W4 = (const u32x4*)((const unsigned short*)outw + (size_t)tid*DD);
        float a0 = 0.0f, a1 = 0.0f, a2 = 0.0f, a3 = 0.0f;
        #pragma unroll
        for (int k = 0; k < 16; ++k) {
            u32x4 w0 = W4[2*k];
            u32x4 w1 = W4[2*k + 1];
#if HAVE_DOT2
            a0 = dot2bf(ypk[8*k+0], w0[0], a0);
            a1 = dot2bf(ypk[8*k+1], w0[1], a1);
            a2 = dot2bf(ypk[8*k+2], w0[2], a2);
            a3 = dot2bf(ypk[8*k+3], w0[3], a3);
            a0 = dot2bf(ypk[8*k+4], w1[0], a0);
            a1 = dot2bf(ypk[8*k+5], w1[1], a1);
            a2 = dot2bf(ypk[8*k+6], w1[2], a2);
            a3 = dot2bf(ypk[8*k+7], w1[3], a3);
#else
            #pragma unroll
            for (int u = 0; u < 4; ++u) {
                unsigned yp0 = ypk[8*k+u], yp1 = ypk[8*k+4+u];
                unsigned wd0 = w0[u], wd1 = w1[u];
                a0 = fmaf(lo2f(yp0), lo2f(wd0), a0);
                a1 = fmaf(hi2f(yp0), hi2f(wd0), a1);
                a2 = fmaf(lo2f(yp1), lo2f(wd1), a2);
                a3 = fmaf(hi2f(yp1), hi2f(wd1), a3);
            }
#endif
        }
        float val = r16((a0 + a1) + (a2 + a3));
        val = r16(val + r16(outb[tid]));
        size_t row = (size_t)(b*NN + i)*DD + tid;
        float v = xres[row] + val;

        float sr = v;
        #pragma unroll
        for (int off = 32; off; off >>= 1) sr += __shfl_xor(sr, off);
        if ((tid & 63) == 0) red2[tid >> 6] = sr;
        __syncthreads();
        float mu = (red2[0] + red2[1] + red2[2] + red2[3]) * (1.0f/256.0f);
        __syncthreads();
        float dd = v - mu;
        float s2 = dd*dd;
        #pragma unroll
        for (int off = 32; off; off >>= 1) s2 += __shfl_xor(s2, off);
        if ((tid & 63) == 0) red2[tid >> 6] = s2;
        __syncthreads();
        float var = (red2[0] + red2[1] + red2[2] + red2[3]) * (1.0f/256.0f);
        float out = dd * (1.0f / sqrtf(var + 1e-5f)) * lng[tid] + lnb[tid];
        xout[row] = out;
        xbout[row] = __float2bfloat16(out);
    }
}

// ---------------------------------------------------------------------------
// add + layernorm, one block per row (f32). Optionally writes bf16 shadow.
// ---------------------------------------------------------------------------
template<bool WRITE_B>
__global__ __launch_bounds__(256) void add_ln_kernel(
    const float* __restrict__ xin, const float* __restrict__ res,
    const float* __restrict__ g, const float* __restrict__ bb,
    float* __restrict__ xout, __hip_bfloat16* __restrict__ xbout)
{
    int r = blockIdx.x; int tid = threadIdx.x;
    float v = xin[r*DD + tid] + res[r*DD + tid];
    __shared__ float red[4];
    float s = v;
    #pragma unroll
    for (int off = 32; off; off >>= 1) s += __shfl_xor(s, off);
    if ((tid & 63) == 0) red[tid >> 6] = s;
    __syncthreads();
    float mu = (red[0] + red[1] + red[2] + red[3]) * (1.0f/256.0f);
    __syncthreads();
    float d = v - mu;
    float s2 = d*d;
    #pragma unroll
    for (int off = 32; off; off >>= 1) s2 += __shfl_xor(s2, off);
    if ((tid & 63) == 0) red[tid >> 6] = s2;
    __syncthreads();
    float var = (red[0] + red[1] + red[2] + red[3]) * (1.0f/256.0f);
    float out = d * (1.0f / sqrtf(var + 1e-5f)) * g[tid] + bb[tid];
    xout[r*DD + tid] = out;
    if (WRITE_B) xbout[r*DD + tid] = __float2bfloat16(out);
}

// ---------------------------------------------------------------------------
extern "C" void kernel_launch(void* const* d_in, const int* in_sizes, int n_in,
                              void* d_out, int out_size, void* d_ws, size_t ws_size,
                              hipStream_t stream)
{
    const float* spectra = (const float*)d_in[0];
    const float* pe      = (const float*)d_in[1];
    const float* latent  = (const float*)d_in[2];
    const float* int_w   = (const float*)d_in[3];
    const float* in_w    = (const float*)d_in[4];
    const float* in_b    = (const float*)d_in[5];
    const float* out_w   = (const float*)d_in[6];
    const float* out_b   = (const float*)d_in[7];
    const float* l1_w    = (const float*)d_in[8];
    const float* l1_b    = (const float*)d_in[9];
    const float* l2_w    = (const float*)d_in[10];
    const float* l2_b    = (const float*)d_in[11];
    const float* n1_g    = (const float*)d_in[12];
    const float* n1_b    = (const float*)d_in[13];
    const float* n2_g    = (const float*)d_in[14];
    const float* n2_b    = (const float*)d_in[15];

    // ---- workspace layout ----
    float* x      = (float*)d_ws;                 // ROWS*256
    float* y2     = x      + ROWS*DD;             // ROWS*256
    float* masses = y2     + ROWS*DD;             // ROWS
    float* maskf  = masses + ROWS;                // ROWS
    float* sqkb   = maskf  + ROWS;                // 16*8*SQS*SQS f32 (13.1MB)
    __hip_bfloat16* bp = (__hip_bfloat16*)(sqkb + (size_t)16*8*SQS*SQS);
    __hip_bfloat16* xb    = bp;  bp += (size_t)MPAD*DD;
    __hip_bfloat16* xqb   = bp;  bp += (size_t)MPAD*DD;
    __hip_bfloat16* qb    = bp;  bp += (size_t)MPAD*DD;
    __hip_bfloat16* kvb   = bp;  bp += (size_t)MPAD*768;
    __hip_bfloat16* yb    = bp;  bp += (size_t)MPAD*DD;    // unused (r22)
    __hip_bfloat16* f1b   = bp;  bp += (size_t)MPAD*FFN_;
    __hip_bfloat16* pekv  = bp;  bp += (size_t)PE_PAD*512;
    __hip_bfloat16* pe_p  = bp;  bp += (size_t)PE_PAD*DD;
    __hip_bfloat16* inw_p = bp;  bp += (size_t)2*768*DD;
    __hip_bfloat16* outw_p= bp;  bp += (size_t)2*DD*DD;
    __hip_bfloat16* l1w_p = bp;  bp += (size_t)2*FFN_*DD;
    __hip_bfloat16* l2w_p = bp;  bp += (size_t)2*DD*FFN_;
    (void)yb;

    dim3 blk(256);
    auto GG = [](int M, int Nc){ return dim3((unsigned)((((M+31)>>5)*(Nc>>5) + 3) / 4)); };
    const unsigned SK256 = (ROWS/16) * (256 >> 5);    // 151*8 = 1208 blocks
    const unsigned SQKG  = (16*8*100 + 3) / 4;        // 3200 blocks

    // ---- build_x + all weight packs, one dispatch ----
    buildpack_kernel<<<ROWS + PACK_BLOCKS, blk, 0, stream>>>(
        spectra, latent, int_w, pe, x, xb, xqb, masses, maskf,
        in_w, inw_p, out_w, outw_p, l1_w, l1w_p, l2_w, l2w_p, pe_p);

    // merged: PEK|PEV GEMM + L0 QKV projection (independent)
    pekv_qkv0_kernel<<<PEKV_BLK + QKV0_BLK, blk, 0, stream>>>(
        pe_p, inw_p + 256*DD, pekv, xqb, xb, inw_p, in_b, qb, kvb);

    // ---------------- layer 0 ----------------
    gemm_sqk<256,512><<<SQKG, blk, 0, stream>>>(qb, kvb, sqkb);
    attn_kernel<true,256,512><<<ROWS, blk, 0, stream>>>(
        qb, kvb + 256, pekv, sqkb, masses, maskf,
        outw_p, out_b, x, n1_g, n1_b, x, xb);
    gemm_mfma<__hip_bfloat16><<<GG(ROWS, 1024), blk, 0, stream>>>(
        xb, l1w_p, l1_b, f1b, ROWS, 1024, 256, 1024, 1);
    gemm_skinny<1024><<<SK256, blk, 0, stream>>>(
        f1b, l2w_p, l2_b, y2, ROWS, 256, 256);
    add_ln_kernel<true><<<ROWS, blk, 0, stream>>>(x, y2, n2_g, n2_b, x, xb);

    // ---------------- layer 1 ----------------
    gemm_mfma<__hip_bfloat16><<<GG(ROWS, 768), blk, 0, stream>>>(
        xb, inw_p + 768*DD, in_b + 768, kvb, ROWS, 768, 256, 768, 0);
    gemm_sqk<768,768><<<SQKG, blk, 0, stream>>>(kvb, kvb + 256, sqkb);
    attn_kernel<false,768,768><<<ROWS, blk, 0, stream>>>(
        kvb, kvb + 512, nullptr, sqkb, masses, maskf,
        outw_p + 256*DD, out_b + 256, x, n1_g + 256, n1_b + 256, x, xb);
    gemm_mfma<__hip_bfloat16><<<GG(ROWS, 1024), blk, 0, stream>>>(
        xb, l1w_p + FFN_*DD, l1_b + 1024, f1b, ROWS, 1024, 256, 1024, 1);
    gemm_skinny<1024><<<SK256, blk, 0, stream>>>(
        f1b, l2w_p + DD*FFN_, l2_b + 256, y2, ROWS, 256, 256);
    add_ln_kernel<false><<<ROWS, blk, 0, stream>>>(x, y2, n2_g + 256, n2_b + 256,
                                                   (float*)d_out, nullptr);
}

// Round 11
// 302.796 us; speedup vs baseline: 1.2027x; 1.2027x over previous
//
#include <hip/hip_runtime.h>
#include <hip/hip_bf16.h>
#include <math.h>

// Problem constants
#define BB 16
#define NP 150
#define NN 151          // N = Np + 1
#define DD 256
#define HH 8
#define HD 32
#define FFN_ 1024
#define PE_LEN 20200
#define ROWS (BB*NN)    // 2416
#define MPAD 2432       // ROWS padded to 32
#define PE_PAD 20224    // PE_LEN padded to 32
#define SQS 160         // Sqk padded row (151->160)

// r21: score distribution (302.8us, absmax 0.0742). r22: fused
// attn+outproj+LN REGRESSED (364us): per-thread W rows = 64 cache lines
// per wave-load, VALUBusy 64->30% (latency-stalled gather). r23: keep the
// fusion, fix coalescing — out_w packed TRANSPOSED as dword pairs at
// buildpack time (owt2[k2*256+gc] = bf16(W[gc][2k2]) | bf16(W[gc][2k2+1])
// <<16; same buffer size as old outw_p). Epilogue reads WT[k2*256+tid]:
// consecutive lanes -> consecutive dwords (256B/wave coalesced), ypk[k2]
// LDS broadcast, 1 dot2/load. Numerics identical to r22 (absmax 0.0742).
// Index semantics: pe0 idx = 10100; rel-bucket clips -> 100 / 20100.

typedef __attribute__((ext_vector_type(8))) short short8;   // 8 bf16 = 4 VGPR
typedef __attribute__((ext_vector_type(4))) float f32x4;
typedef __attribute__((ext_vector_type(4))) unsigned u32x4; // 4 dwords

#if defined(__has_builtin)
#if __has_builtin(__builtin_amdgcn_fdot2_f32_bf16)
#define HAVE_DOT2 1
#endif
#endif
#ifndef HAVE_DOT2
#define HAVE_DOT2 0
#endif

__device__ __forceinline__ float r16(float x) {
    return __bfloat162float(__float2bfloat16(x));   // RNE bf16 grid
}
__device__ __forceinline__ float us2f(unsigned short u) {
    return __uint_as_float((unsigned)u << 16);      // bf16 bits -> f32
}
__device__ __forceinline__ float lo2f(unsigned x) {
    return __uint_as_float(x << 16);                // low bf16 of dword
}
__device__ __forceinline__ float hi2f(unsigned x) {
    return __uint_as_float(x & 0xFFFF0000u);        // high bf16 of dword
}
__device__ __forceinline__ unsigned short f2us(float x) {
    __hip_bfloat16 h = __float2bfloat16(x);
    return *reinterpret_cast<unsigned short*>(&h);  // RNE bf16 bits
}
__device__ __forceinline__ unsigned cvtpk(float lo, float hi) {
    unsigned r;                                     // D.lo=bf16(lo) D.hi=bf16(hi), RNE
    asm("v_cvt_pk_bf16_f32 %0, %1, %2" : "=v"(r) : "v"(lo), "v"(hi));
    return r;
}
#if HAVE_DOT2
typedef __attribute__((ext_vector_type(2))) __bf16 bf16x2;
__device__ __forceinline__ float dot2bf(unsigned a, unsigned b, float acc) {
    bf16x2 av = __builtin_bit_cast(bf16x2, a);
    bf16x2 bv = __builtin_bit_cast(bf16x2, b);
    return __builtin_amdgcn_fdot2_f32_bf16(av, bv, acc, false);
}
#endif

// ---------------------------------------------------------------------------
// build_x (+ fused weight packs on trailing blocks).
// owt2: out_w transposed dword-pair pack (see header comment).
// ---------------------------------------------------------------------------
#define PACK_BLOCKS 1024
__global__ __launch_bounds__(256) void buildpack_kernel(
    const float* __restrict__ spectra, const float* __restrict__ latent,
    const float* __restrict__ int_w, const float* __restrict__ pe,
    float* __restrict__ x, __hip_bfloat16* __restrict__ xb,
    __hip_bfloat16* __restrict__ xqb,
    float* __restrict__ masses, float* __restrict__ maskf,
    const float* __restrict__ in_w,  __hip_bfloat16* __restrict__ inw_p,
    const float* __restrict__ out_w, unsigned* __restrict__ owt2,
    const float* __restrict__ l1_w,  __hip_bfloat16* __restrict__ l1w_p,
    const float* __restrict__ l2_w,  __hip_bfloat16* __restrict__ l2w_p,
    __hip_bfloat16* __restrict__ pe_p)
{
    int tid = threadIdx.x;
    if (blockIdx.x < ROWS) {
        int bn = blockIdx.x;            // b*NN + n
        int b = bn / NN, n = bn % NN;
        float val;
        if (n == 0) {
            val = latent[tid];
            if (tid == 0) { masses[bn] = 0.0f; maskf[bn] = 0.0f; }
        } else {
            float mz = spectra[(b*NP + n - 1)*2 + 0];
            float it = spectra[(b*NP + n - 1)*2 + 1];
            int i = (tid < 128) ? tid : tid - 128;
            const double base_d = 0.001 / (2.0 * 3.141592653589793);
            double term_d = base_d * pow(1.0e7, (double)i / 127.0);
            float tf = (float)term_d;                   // .astype(np.float32)
            double arg = (double)mz / (double)tf;
            double sv = (tid < 128) ? sin(arg) : cos(arg);
            val = (float)sv + it * int_w[tid];
            if (tid == 0) {
                masses[bn] = mz;
                maskf[bn] = ((mz + it) == 0.0f) ? 1.0f : 0.0f;
            }
        }
        x[bn*DD + tid] = val;
        xb[bn*DD + tid] = __float2bfloat16(val);
        xqb[bn*DD + tid] = __float2bfloat16(val + pe[10100*DD + tid]);
    } else {
        long long base = (long long)(blockIdx.x - ROWS) * 256 + tid;
        const long long stride = (long long)PACK_BLOCKS * 256;
        for (long long i = base; i < (long long)PE_PAD*DD; i += stride)
            pe_p[i] = __float2bfloat16(i < (long long)PE_LEN*DD ? pe[i] : 0.0f);
        for (long long i = base; i < 2LL*768*DD; i += stride)
            inw_p[i] = __float2bfloat16(in_w[i]);
        for (long long i = base; i < 2LL*128*256; i += stride) {
            long long l = i / (128*256), rem = i % (128*256);
            long long k2 = rem / 256, gc = rem % 256;
            const float* src = out_w + l*DD*DD + gc*DD + 2*k2;
            owt2[i] = (unsigned)f2us(src[0]) | ((unsigned)f2us(src[1]) << 16);
        }
        for (long long i = base; i < 2LL*FFN_*DD; i += stride)
            l1w_p[i] = __float2bfloat16(l1_w[i]);
        for (long long i = base; i < 2LL*DD*FFN_; i += stride)
            l2w_p[i] = __float2bfloat16(l2_w[i]);
    }
}

// ---------------------------------------------------------------------------
// MFMA GEMM: C[M,Nc] = A(bf16) @ W(bf16)^T, f32 acc, epilogue
// r16(r16(acc)+r16(bias)). One wave per 32x32 tile. (wide-Nc ROWS GEMMs.)
// ---------------------------------------------------------------------------
template<typename CT>
__global__ __launch_bounds__(256) void gemm_mfma(
    const __hip_bfloat16* __restrict__ A, const __hip_bfloat16* __restrict__ W,
    const float* __restrict__ bias, CT* __restrict__ C,
    int M, int Nc, int K, int ldc, int relu)
{
    int wave = threadIdx.x >> 6;
    int lane = threadIdx.x & 63;
    int NT = Nc >> 5;
    int MT = (M + 31) >> 5;
    int id = blockIdx.x * 4 + wave;
    if (id >= MT * NT) return;
    int mt = id / NT, nt = id % NT;
    int m0 = mt * 32, n0 = nt * 32;
    int rl = lane & 15, q8 = (lane >> 4) * 8;

    const short8* Ap0 = (const short8*)(A + (size_t)(m0 + rl)*K + q8);
    const short8* Ap1 = (const short8*)(A + (size_t)(m0 + 16 + rl)*K + q8);
    const short8* Wp0 = (const short8*)(W + (size_t)(n0 + rl)*K + q8);
    const short8* Wp1 = (const short8*)(W + (size_t)(n0 + 16 + rl)*K + q8);

    f32x4 acc00 = {0,0,0,0}, acc01 = {0,0,0,0};
    f32x4 acc10 = {0,0,0,0}, acc11 = {0,0,0,0};
    int steps = K >> 5;
    for (int s = 0; s < steps; ++s) {
        short8 a0 = Ap0[s*4];
        short8 a1 = Ap1[s*4];
        short8 b0 = Wp0[s*4];
        short8 b1 = Wp1[s*4];
        acc00 = __builtin_amdgcn_mfma_f32_16x16x32_bf16(a0, b0, acc00, 0, 0, 0);
        acc01 = __builtin_amdgcn_mfma_f32_16x16x32_bf16(a0, b1, acc01, 0, 0, 0);
        acc10 = __builtin_amdgcn_mfma_f32_16x16x32_bf16(a1, b0, acc10, 0, 0, 0);
        acc11 = __builtin_amdgcn_mfma_f32_16x16x32_bf16(a1, b1, acc11, 0, 0, 0);
    }

    int rbase = (lane >> 4) * 4;
    #pragma unroll
    for (int sm = 0; sm < 2; ++sm) {
        #pragma unroll
        for (int sn = 0; sn < 2; ++sn) {
            f32x4 a = (sm == 0) ? (sn == 0 ? acc00 : acc01)
                                : (sn == 0 ? acc10 : acc11);
            int gc = n0 + sn*16 + rl;
            float bv = bias ? r16(bias[gc]) : 0.0f;
            #pragma unroll
            for (int rg = 0; rg < 4; ++rg) {
                int gr = m0 + sm*16 + rbase + rg;
                if (gr < M) {
                    float val = r16(a[rg]);
                    if (bias) val = r16(val + bv);
                    if (relu) val = fmaxf(val, 0.0f);
                    C[(size_t)gr*ldc + gc] = (CT)val;
                }
            }
        }
    }
}

// ---------------------------------------------------------------------------
// Skinny GEMM for Nc=256 (FFN-down): one 16x32 tile per BLOCK, K split
// across the 4 waves, LDS partial reduce, distributed epilogue.
// ---------------------------------------------------------------------------
template<int K>
__global__ __launch_bounds__(256) void gemm_skinny(
    const __hip_bfloat16* __restrict__ A, const __hip_bfloat16* __restrict__ W,
    const float* __restrict__ bias, float* __restrict__ C,
    int M, int Nc, int ldc)
{
    int NT = Nc >> 5;
    int id = blockIdx.x;
    int mt = id / NT, nt = id % NT;
    int m0 = mt * 16, n0 = nt * 32;
    int wave = threadIdx.x >> 6;
    int lane = threadIdx.x & 63;
    int rl = lane & 15, q8 = (lane >> 4) * 8;
    const int K4 = K >> 2;              // K slice per wave
    int k0 = wave * K4;

    const short8* Ap  = (const short8*)(A + (size_t)(m0 + rl)*K + k0 + q8);
    const short8* Wp0 = (const short8*)(W + (size_t)(n0 + rl)*K + k0 + q8);
    const short8* Wp1 = (const short8*)(W + (size_t)(n0 + 16 + rl)*K + k0 + q8);

    f32x4 acc0 = {0,0,0,0}, acc1 = {0,0,0,0};
    #pragma unroll
    for (int s = 0; s < K4/32; ++s) {
        short8 a  = Ap[s*4];
        short8 b0 = Wp0[s*4];
        short8 b1 = Wp1[s*4];
        acc0 = __builtin_amdgcn_mfma_f32_16x16x32_bf16(a, b0, acc0, 0, 0, 0);
        acc1 = __builtin_amdgcn_mfma_f32_16x16x32_bf16(a, b1, acc1, 0, 0, 0);
    }

    __shared__ float red[4][8][65];     // [wave][slot][lane] pad->no conflicts
    #pragma unroll
    for (int rg = 0; rg < 4; ++rg) {
        red[wave][rg][lane]   = acc0[rg];
        red[wave][4+rg][lane] = acc1[rg];
    }
    __syncthreads();

    #pragma unroll
    for (int t = 0; t < 2; ++t) {
        int sl = wave*2 + t;
        float s = red[0][sl][lane] + red[1][sl][lane]
                + red[2][sl][lane] + red[3][sl][lane];
        int rg = sl & 3, sn = sl >> 2;
        int gr = m0 + (lane >> 4)*4 + rg;
        int gc = n0 + sn*16 + rl;
        float val = r16(s);
        val = r16(val + r16(bias[gc]));
        if (gr < M) C[(size_t)gr*ldc + gc] = val;
    }
}

// ---------------------------------------------------------------------------
// Batched score GEMM: Sqk[b][h][i][j] = sum_d Q[b,i,h*32+d] * K[b,j,h*32+d],
// f32, unscaled, unmasked. One 16x16 (i x j) tile per wave, K=32 = 1 MFMA.
// ---------------------------------------------------------------------------
template<int QS, int KS>
__global__ __launch_bounds__(256) void gemm_sqk(
    const __hip_bfloat16* __restrict__ Q, const __hip_bfloat16* __restrict__ Kp,
    float* __restrict__ S)
{
    int wave = threadIdx.x >> 6;
    int lane = threadIdx.x & 63;
    int id = blockIdx.x * 4 + wave;         // b(16) x h(8) x it(10) x jt(10)
    if (id >= 16*8*100) return;
    int jt = id % 10, it = (id / 10) % 10;
    int h = (id / 100) & 7, b = id / 800;
    int i0 = it * 16, j0 = jt * 16;
    int rl = lane & 15, q8 = (lane >> 4) * 8;

    short8 a  = *(const short8*)(Q  + (size_t)(b*NN + i0 + rl)*QS + h*32 + q8);
    short8 kb = *(const short8*)(Kp + (size_t)(b*NN + j0 + rl)*KS + h*32 + q8);
    f32x4 acc = {0,0,0,0};
    acc = __builtin_amdgcn_mfma_f32_16x16x32_bf16(a, kb, acc, 0, 0, 0);

    float* Sb = S + ((size_t)(b*8 + h))*SQS*SQS;
    int rbase = (lane >> 4) * 4;
    #pragma unroll
    for (int rg = 0; rg < 4; ++rg) {
        int ii = i0 + rbase + rg, jj = j0 + rl;
        if (ii < NN && jj < NN)
            Sb[(size_t)ii*SQS + jj] = acc[rg];
    }
}

// ---------------------------------------------------------------------------
// Merged pekv GEMM + L0 QKV projection (independent, both read weight packs).
// ---------------------------------------------------------------------------
#define PEKV_BLK 632u   // ceil(158*16 tiles / 4 waves)
#define QKV0_BLK 456u   // ceil(76*24 tiles / 4 waves)

__device__ __forceinline__ void pekv_body(
    unsigned bid, int wave, int lane,
    const __hip_bfloat16* __restrict__ A, const __hip_bfloat16* __restrict__ W,
    __hip_bfloat16* __restrict__ C)
{
    const int K = 256, Nc = 512, ldc = 512, M = PE_LEN;
    int NT = Nc >> 5;
    int MT4 = (M + 127) >> 7;
    int id = bid * 4 + wave;
    if (id >= MT4 * NT) return;
    int mt = id / NT, nt = id % NT;
    int m0 = mt * 128, n0 = nt * 32;
    int rl = lane & 15, q8 = (lane >> 4) * 8;

    const short8* Ab  = (const short8*)(A + (size_t)(m0 + rl)*K + q8);
    const short8* Wp0 = (const short8*)(W + (size_t)(n0 + rl)*K + q8);
    const short8* Wp1 = (const short8*)(W + (size_t)(n0 + 16 + rl)*K + q8);
    const int rstep = K >> 3;                  // short8 units per row

    f32x4 acc[4][2][2] = {};
    for (int s = 0; s < 8; ++s) {              // K/32 = 8
        short8 b0 = Wp0[s*4];
        short8 b1 = Wp1[s*4];
        short8 a[4][2];
        #pragma unroll
        for (int t = 0; t < 4; ++t) {
            a[t][0] = Ab[(size_t)(t*32)*rstep + s*4];
            a[t][1] = Ab[(size_t)(t*32+16)*rstep + s*4];
        }
        #pragma unroll
        for (int t = 0; t < 4; ++t) {
            acc[t][0][0] = __builtin_amdgcn_mfma_f32_16x16x32_bf16(a[t][0], b0, acc[t][0][0], 0, 0, 0);
            acc[t][0][1] = __builtin_amdgcn_mfma_f32_16x16x32_bf16(a[t][0], b1, acc[t][0][1], 0, 0, 0);
            acc[t][1][0] = __builtin_amdgcn_mfma_f32_16x16x32_bf16(a[t][1], b0, acc[t][1][0], 0, 0, 0);
            acc[t][1][1] = __builtin_amdgcn_mfma_f32_16x16x32_bf16(a[t][1], b1, acc[t][1][1], 0, 0, 0);
        }
    }

    int rbase = (lane >> 4) * 4;
    #pragma unroll
    for (int t = 0; t < 4; ++t) {
        #pragma unroll
        for (int sm = 0; sm < 2; ++sm) {
            #pragma unroll
            for (int sn = 0; sn < 2; ++sn) {
                f32x4 a = acc[t][sm][sn];
                int gc = n0 + sn*16 + rl;
                #pragma unroll
                for (int rg = 0; rg < 4; ++rg) {
                    int gr = m0 + t*32 + sm*16 + rbase + rg;
                    if (gr < M)
                        C[(size_t)gr*ldc + gc] = (__hip_bfloat16)r16(a[rg]);
                }
            }
        }
    }
}

__device__ __forceinline__ void qkv0_body(
    unsigned bid, int wave, int lane,
    const __hip_bfloat16* __restrict__ xqb, const __hip_bfloat16* __restrict__ xb,
    const __hip_bfloat16* __restrict__ inw_p, const float* __restrict__ in_b,
    __hip_bfloat16* __restrict__ qb, __hip_bfloat16* __restrict__ kvb, int M)
{
    int MT = (M + 31) >> 5;
    int id = bid * 4 + wave;
    if (id >= MT * 24) return;
    int mt = id / 24, ntt = id % 24;
    bool isQ = (ntt < 8);
    const __hip_bfloat16* A = isQ ? xqb : xb;
    const __hip_bfloat16* W = inw_p + (isQ ? (size_t)ntt*32*DD
                                           : (size_t)(256 + (ntt-8)*32)*DD);
    const float* bias = in_b + (isQ ? ntt*32 : 256 + (ntt-8)*32);
    __hip_bfloat16* C = isQ ? qb : kvb;
    int ldc = isQ ? 256 : 512;
    int cbase = isQ ? ntt*32 : (ntt-8)*32;
    int m0 = mt * 32;
    int rl = lane & 15, q8 = (lane >> 4) * 8;
    const int K = DD;

    const short8* Ap0 = (const short8*)(A + (size_t)(m0 + rl)*K + q8);
    const short8* Ap1 = (const short8*)(A + (size_t)(m0 + 16 + rl)*K + q8);
    const short8* Wp0 = (const short8*)(W + (size_t)(rl)*K + q8);
    const short8* Wp1 = (const short8*)(W + (size_t)(16 + rl)*K + q8);

    f32x4 acc00 = {0,0,0,0}, acc01 = {0,0,0,0};
    f32x4 acc10 = {0,0,0,0}, acc11 = {0,0,0,0};
    for (int s = 0; s < K/32; ++s) {
        short8 a0 = Ap0[s*4];
        short8 a1 = Ap1[s*4];
        short8 b0 = Wp0[s*4];
        short8 b1 = Wp1[s*4];
        acc00 = __builtin_amdgcn_mfma_f32_16x16x32_bf16(a0, b0, acc00, 0, 0, 0);
        acc01 = __builtin_amdgcn_mfma_f32_16x16x32_bf16(a0, b1, acc01, 0, 0, 0);
        acc10 = __builtin_amdgcn_mfma_f32_16x16x32_bf16(a1, b0, acc10, 0, 0, 0);
        acc11 = __builtin_amdgcn_mfma_f32_16x16x32_bf16(a1, b1, acc11, 0, 0, 0);
    }

    int rbase = (lane >> 4) * 4;
    #pragma unroll
    for (int sm = 0; sm < 2; ++sm) {
        #pragma unroll
        for (int sn = 0; sn < 2; ++sn) {
            f32x4 a = (sm == 0) ? (sn == 0 ? acc00 : acc01)
                                : (sn == 0 ? acc10 : acc11);
            int gc = cbase + sn*16 + rl;
            float bv = r16(bias[sn*16 + rl]);
            #pragma unroll
            for (int rg = 0; rg < 4; ++rg) {
                int gr = m0 + sm*16 + rbase + rg;
                if (gr < M) {
                    float val = r16(a[rg]);
                    val = r16(val + bv);
                    C[(size_t)gr*ldc + gc] = (__hip_bfloat16)val;
                }
            }
        }
    }
}

__global__ __launch_bounds__(256) void pekv_qkv0_kernel(
    const __hip_bfloat16* __restrict__ pe_p, const __hip_bfloat16* __restrict__ wkv0,
    __hip_bfloat16* __restrict__ pekv,
    const __hip_bfloat16* __restrict__ xqb, const __hip_bfloat16* __restrict__ xb,
    const __hip_bfloat16* __restrict__ inw_p, const float* __restrict__ in_b,
    __hip_bfloat16* __restrict__ qb, __hip_bfloat16* __restrict__ kvb)
{
    int wave = threadIdx.x >> 6;
    int lane = threadIdx.x & 63;
    if (blockIdx.x < PEKV_BLK)
        pekv_body(blockIdx.x, wave, lane, pe_p, wkv0, pekv);
    else
        qkv0_body(blockIdx.x - PEKV_BLK, wave, lane, xqb, xb, inw_p, in_b,
                  qb, kvb, ROWS);
}

// ---------------------------------------------------------------------------
// Fused attention + out-proj + residual + layernorm. One block per (b,i),
// b = blk&15 (XCD locality). Thread (g = tid>>5, c = tid&31).
// Scores: Sqk preload; USE_PE adds PE-gather dot (Phase A). Phase B as r21.
// Epilogue: y row -> bf16 pairs (ypk, LDS broadcast) -> per-thread 256-dot
// vs TRANSPOSED dword-paired out_w (WT[k2*256+tid]: coalesced) ->
// r16(r16(dot)+r16(bias)) -> residual -> LN -> xout/xbout.
// ---------------------------------------------------------------------------
template<bool USE_PE, int QS, int VS>
__global__ __launch_bounds__(256) void attn_kernel(
    const __hip_bfloat16* __restrict__ qp,
    const __hip_bfloat16* __restrict__ vp,
    const __hip_bfloat16* __restrict__ pekv,
    const float* __restrict__ sqk,
    const float* __restrict__ masses, const float* __restrict__ maskf,
    const unsigned* __restrict__ outwT, const float* __restrict__ outb,
    const float* __restrict__ xres,
    const float* __restrict__ lng, const float* __restrict__ lnb,
    float* __restrict__ xout, __hip_bfloat16* __restrict__ xbout)
{
    int b = blockIdx.x & 15;        // XCD-locality swizzle (pure permutation)
    int i = blockIdx.x >> 4;
    int tid = threadIdx.x;
    int c = tid & 31;               // 8-column chunk index
    int g = tid >> 5;               // row-residue class
    int h = c >> 2;                 // head owning columns c*8..c*8+7
    const float scale = 0.17677669529663687f;   // 1/sqrt(32)

    __shared__ float sc[HH][152];
    __shared__ float msh[152];
    __shared__ int   tj[152];
    __shared__ __align__(16) float part[8][264];
    __shared__ float yrow[256];
    __shared__ unsigned ypk[128];
    __shared__ float red2[4];

    if (tid < NN) {
        float mval = maskf[b*NN + tid];
        msh[tid] = mval;
        if (USE_PE) {
            double m = (double)masses[b*NN + tid] - (double)masses[b*NN + i];
            m = fmin(fmax(m, -100.0), 100.0);
            tj[tid] = (int)(((m + 1.0) + 100.0) / 0.01);  // f64: clips 100/20100
        }
        // preload Sqk rows (coalesced in j)
        const float* Sb = sqk + ((size_t)(b*8))*SQS*SQS + (size_t)i*SQS + tid;
        if (USE_PE) {
            #pragma unroll
            for (int hh = 0; hh < 8; ++hh)
                sc[hh][tid] = Sb[(size_t)hh*SQS*SQS];     // raw; PE+scale+mask in Phase A
        } else {
            #pragma unroll
            for (int hh = 0; hh < 8; ++hh) {
                float s = Sb[(size_t)hh*SQS*SQS] * scale;
                sc[hh][tid] = (mval != 0.0f) ? -1e9f : s;
            }
        }
    }

    // preload Q chunk (only needed for the PE dot)
    unsigned qw[4];
#if !HAVE_DOT2
    float qf[8];
#endif
    if (USE_PE) {
        const u32x4 q4 = *(const u32x4*)((const unsigned short*)qp
                            + (size_t)(b*NN + i)*QS + c*8);
        qw[0] = q4[0]; qw[1] = q4[1]; qw[2] = q4[2]; qw[3] = q4[3];
#if !HAVE_DOT2
        #pragma unroll
        for (int w = 0; w < 4; ++w) { qf[2*w] = lo2f(qw[w]); qf[2*w+1] = hi2f(qw[w]); }
#endif
    }
    __syncthreads();

    const unsigned short* vbase = (const unsigned short*)vp + (size_t)(b*NN)*VS + c*8;
    const unsigned short* pkb = (const unsigned short*)pekv + c*8;        // PEK col
    const unsigned short* pvb = (const unsigned short*)pekv + 256 + c*8;  // PEV col

    // ---- Phase A (USE_PE only): PE-gather dot added to preloaded Sqk ----
    if (USE_PE) {
        int j = g;
        u32x4 pcur = *(const u32x4*)(pkb + (size_t)tj[j]*512);
        for (int p = 0; p < 19; ++p) {
            int jn = j + 8;
            bool more = (jn < NN);
            u32x4 pn;
            if (more) pn = *(const u32x4*)(pkb + (size_t)tj[jn]*512);
            float acc = 0.0f;
#if HAVE_DOT2
            #pragma unroll
            for (int w = 0; w < 4; ++w) acc = dot2bf(qw[w], pcur[w], acc);
#else
            #pragma unroll
            for (int w = 0; w < 4; ++w) {
                acc = fmaf(qf[2*w],   lo2f(pcur[w]), acc);
                acc = fmaf(qf[2*w+1], hi2f(pcur[w]), acc);
            }
#endif
            acc += __shfl_xor(acc, 1);
            acc += __shfl_xor(acc, 2);
            if ((c & 3) == 0) {
                float s = (sc[h][j] + acc) * scale;
                if (msh[j] != 0.0f) s = -1e9f;
                sc[h][j] = s;
            }
            if (!more) break;
            j = jn; pcur = pn;
        }
        __syncthreads();
    }

    // ---- softmax per head, f32, within 32-lane group (head = g) ----
    {
        int lane = tid & 31;
        int hh = g;
        float mx = -INFINITY;
        for (int j = lane; j < NN; j += 32) mx = fmaxf(mx, sc[hh][j]);
        #pragma unroll
        for (int off = 16; off; off >>= 1) mx = fmaxf(mx, __shfl_xor(mx, off, 32));
        float sum = 0.0f;
        for (int j = lane; j < NN; j += 32) {
            float e = expf(sc[hh][j] - mx);
            sc[hh][j] = e;
            sum += e;
        }
        #pragma unroll
        for (int off = 16; off; off >>= 1) sum += __shfl_xor(sum, off, 32);
        float inv = 1.0f / sum;
        for (int j = lane; j < NN; j += 32) sc[hh][j] = r16(sc[hh][j] * inv); // bf16(a)
    }
    __syncthreads();

    // ---- Phase B: partial y over row class, then cross-group reduce ----
    {
        float ya[8];
        #pragma unroll
        for (int u = 0; u < 8; ++u) ya[u] = 0.0f;

#if HAVE_DOT2
        // rows paired (jA = g+16t, jB = jA+8), t = 0..8; tail row g+144 if valid
        u32x4 vA = *(const u32x4*)(vbase + (size_t)g*VS);
        u32x4 vB = *(const u32x4*)(vbase + (size_t)(g+8)*VS);
        u32x4 pA, pB;
        if (USE_PE) {
            pA = *(const u32x4*)(pvb + (size_t)tj[g]*512);
            pB = *(const u32x4*)(pvb + (size_t)tj[g+8]*512);
        }
        for (int t = 0; t < 9; ++t) {
            int jA = g + t*16, jB = jA + 8;
            u32x4 nvA, nvB, npA, npB;
            if (t < 8) {
                int nA = jA + 16, nB = jB + 16;
                nvA = *(const u32x4*)(vbase + (size_t)nA*VS);
                nvB = *(const u32x4*)(vbase + (size_t)nB*VS);
                if (USE_PE) {
                    npA = *(const u32x4*)(pvb + (size_t)tj[nA]*512);
                    npB = *(const u32x4*)(pvb + (size_t)tj[nB]*512);
                }
            }
            unsigned apair = cvtpk(sc[h][jA], sc[h][jB]);   // lo=aA hi=aB
            #pragma unroll
            for (int w = 0; w < 4; ++w) {
                unsigned lopair, hipair;
                if (USE_PE) {
                    float sA0 = lo2f(vA[w]) + lo2f(pA[w]);
                    float sA1 = hi2f(vA[w]) + hi2f(pA[w]);
                    float sB0 = lo2f(vB[w]) + lo2f(pB[w]);
                    float sB1 = hi2f(vB[w]) + hi2f(pB[w]);
                    lopair = cvtpk(sA0, sB0);
                    hipair = cvtpk(sA1, sB1);
                } else {
                    lopair = __builtin_amdgcn_perm(vB[w], vA[w], 0x05040100u);
                    hipair = __builtin_amdgcn_perm(vB[w], vA[w], 0x07060302u);
                }
                ya[2*w]   = dot2bf(apair, lopair, ya[2*w]);
                ya[2*w+1] = dot2bf(apair, hipair, ya[2*w+1]);
            }
            if (t < 8) {
                vA = nvA; vB = nvB;
                if (USE_PE) { pA = npA; pB = npB; }
            }
        }
        if (g + 144 < NN) {                 // tail row (g < 7)
            int jT = g + 144;
            u32x4 v = *(const u32x4*)(vbase + (size_t)jT*VS);
            u32x4 pq;
            if (USE_PE) pq = *(const u32x4*)(pvb + (size_t)tj[jT]*512);
            float aT = sc[h][jT];
            #pragma unroll
            for (int w = 0; w < 4; ++w) {
                float v0 = lo2f(v[w]), v1 = hi2f(v[w]);
                if (USE_PE) {
                    unsigned pk2 = cvtpk(v0 + lo2f(pq[w]), v1 + hi2f(pq[w]));
                    v0 = lo2f(pk2); v1 = hi2f(pk2);
                }
                ya[2*w]   = fmaf(aT, v0, ya[2*w]);
                ya[2*w+1] = fmaf(aT, v1, ya[2*w+1]);
            }
        }
#else
        int j = g;
        u32x4 vcur = *(const u32x4*)(vbase + (size_t)j*VS);
        u32x4 pcur;
        if (USE_PE) pcur = *(const u32x4*)(pvb + (size_t)tj[j]*512);
        float acur = sc[h][j];
        for (int p = 0; p < 19; ++p) {
            int jn = j + 8;
            bool more = (jn < NN);
            u32x4 vn, pn;
            float an = 0.0f;
            if (more) {
                vn = *(const u32x4*)(vbase + (size_t)jn*VS);
                if (USE_PE) pn = *(const u32x4*)(pvb + (size_t)tj[jn]*512);
                an = sc[h][jn];
            }
            #pragma unroll
            for (int w = 0; w < 4; ++w) {
                float v0 = lo2f(vcur[w]), v1 = hi2f(vcur[w]);
                if (USE_PE) {
                    v0 = r16(v0 + lo2f(pcur[w]));
                    v1 = r16(v1 + hi2f(pcur[w]));
                }
                ya[2*w]   = fmaf(acur, v0, ya[2*w]);
                ya[2*w+1] = fmaf(acur, v1, ya[2*w+1]);
            }
            if (!more) break;
            j = jn; vcur = vn; acur = an;
            if (USE_PE) pcur = pn;
        }
#endif
        f32x4* pp = (f32x4*)&part[g][c*8];
        pp[0] = f32x4{ya[0], ya[1], ya[2], ya[3]};
        pp[1] = f32x4{ya[4], ya[5], ya[6], ya[7]};
    }
    __syncthreads();

    // ---- fused out-proj + residual + layernorm (row-local) ----
    {
        float s = part[0][tid];
        #pragma unroll
        for (int g2 = 1; g2 < 8; ++g2) s += part[g2][tid];
        yrow[tid] = s;
    }
    __syncthreads();
    if (tid < 128) ypk[tid] = cvtpk(yrow[2*tid], yrow[2*tid + 1]);  // bf16 y operand
    __syncthreads();
    {
        float a0 = 0.0f, a1 = 0.0f, a2 = 0.0f, a3 = 0.0f;
        #pragma unroll
        for (int k2 = 0; k2 < 128; k2 += 4) {
            unsigned w0 = outwT[(size_t)(k2+0)*256 + tid];
            unsigned w1 = outwT[(size_t)(k2+1)*256 + tid];
            unsigned w2 = outwT[(size_t)(k2+2)*256 + tid];
            unsigned w3 = outwT[(size_t)(k2+3)*256 + tid];
#if HAVE_DOT2
            a0 = dot2bf(ypk[k2+0], w0, a0);
            a1 = dot2bf(ypk[k2+1], w1, a1);
            a2 = dot2bf(ypk[k2+2], w2, a2);
            a3 = dot2bf(ypk[k2+3], w3, a3);
#else
            a0 = fmaf(lo2f(ypk[k2+0]), lo2f(w0), a0);
            a1 = fmaf(hi2f(ypk[k2+0]), hi2f(w0), a1);
            a2 = fmaf(lo2f(ypk[k2+1]), lo2f(w1), a2);
            a3 = fmaf(hi2f(ypk[k2+1]), hi2f(w1), a3);
            a0 = fmaf(lo2f(ypk[k2+2]), lo2f(w2), a0);
            a1 = fmaf(hi2f(ypk[k2+2]), hi2f(w2), a1);
            a2 = fmaf(lo2f(ypk[k2+3]), lo2f(w3), a2);
            a3 = fmaf(hi2f(ypk[k2+3]), hi2f(w3), a3);
#endif
        }
        float val = r16((a0 + a1) + (a2 + a3));
        val = r16(val + r16(outb[tid]));
        size_t row = (size_t)(b*NN + i)*DD + tid;
        float v = xres[row] + val;

        float sr = v;
        #pragma unroll
        for (int off = 32; off; off >>= 1) sr += __shfl_xor(sr, off);
        if ((tid & 63) == 0) red2[tid >> 6] = sr;
        __syncthreads();
        float mu = (red2[0] + red2[1] + red2[2] + red2[3]) * (1.0f/256.0f);
        __syncthreads();
        float dd = v - mu;
        float s2 = dd*dd;
        #pragma unroll
        for (int off = 32; off; off >>= 1) s2 += __shfl_xor(s2, off);
        if ((tid & 63) == 0) red2[tid >> 6] = s2;
        __syncthreads();
        float var = (red2[0] + red2[1] + red2[2] + red2[3]) * (1.0f/256.0f);
        float out = dd * (1.0f / sqrtf(var + 1e-5f)) * lng[tid] + lnb[tid];
        xout[row] = out;
        xbout[row] = __float2bfloat16(out);
    }
}

// ---------------------------------------------------------------------------
// add + layernorm, one block per row (f32). Optionally writes bf16 shadow.
// ---------------------------------------------------------------------------
template<bool WRITE_B>
__global__ __launch_bounds__(256) void add_ln_kernel(
    const float* __restrict__ xin, const float* __restrict__ res,
    const float* __restrict__ g, const float* __restrict__ bb,
    float* __restrict__ xout, __hip_bfloat16* __restrict__ xbout)
{
    int r = blockIdx.x; int tid = threadIdx.x;
    float v = xin[r*DD + tid] + res[r*DD + tid];
    __shared__ float red[4];
    float s = v;
    #pragma unroll
    for (int off = 32; off; off >>= 1) s += __shfl_xor(s, off);
    if ((tid & 63) == 0) red[tid >> 6] = s;
    __syncthreads();
    float mu = (red[0] + red[1] + red[2] + red[3]) * (1.0f/256.0f);
    __syncthreads();
    float d = v - mu;
    float s2 = d*d;
    #pragma unroll
    for (int off = 32; off; off >>= 1) s2 += __shfl_xor(s2, off);
    if ((tid & 63) == 0) red[tid >> 6] = s2;
    __syncthreads();
    float var = (red[0] + red[1] + red[2] + red[3]) * (1.0f/256.0f);
    float out = d * (1.0f / sqrtf(var + 1e-5f)) * g[tid] + bb[tid];
    xout[r*DD + tid] = out;
    if (WRITE_B) xbout[r*DD + tid] = __float2bfloat16(out);
}

// ---------------------------------------------------------------------------
extern "C" void kernel_launch(void* const* d_in, const int* in_sizes, int n_in,
                              void* d_out, int out_size, void* d_ws, size_t ws_size,
                              hipStream_t stream)
{
    const float* spectra = (const float*)d_in[0];
    const float* pe      = (const float*)d_in[1];
    const float* latent  = (const float*)d_in[2];
    const float* int_w   = (const float*)d_in[3];
    const float* in_w    = (const float*)d_in[4];
    const float* in_b    = (const float*)d_in[5];
    const float* out_w   = (const float*)d_in[6];
    const float* out_b   = (const float*)d_in[7];
    const float* l1_w    = (const float*)d_in[8];
    const float* l1_b    = (const float*)d_in[9];
    const float* l2_w    = (const float*)d_in[10];
    const float* l2_b    = (const float*)d_in[11];
    const float* n1_g    = (const float*)d_in[12];
    const float* n1_b    = (const float*)d_in[13];
    const float* n2_g    = (const float*)d_in[14];
    const float* n2_b    = (const float*)d_in[15];

    // ---- workspace layout ----
    float* x      = (float*)d_ws;                 // ROWS*256
    float* y2     = x      + ROWS*DD;             // ROWS*256
    float* masses = y2     + ROWS*DD;             // ROWS
    float* maskf  = masses + ROWS;                // ROWS
    float* sqkb   = maskf  + ROWS;                // 16*8*SQS*SQS f32 (13.1MB)
    __hip_bfloat16* bp = (__hip_bfloat16*)(sqkb + (size_t)16*8*SQS*SQS);
    __hip_bfloat16* xb    = bp;  bp += (size_t)MPAD*DD;
    __hip_bfloat16* xqb   = bp;  bp += (size_t)MPAD*DD;
    __hip_bfloat16* qb    = bp;  bp += (size_t)MPAD*DD;
    __hip_bfloat16* kvb   = bp;  bp += (size_t)MPAD*768;
    __hip_bfloat16* f1b   = bp;  bp += (size_t)MPAD*FFN_;
    __hip_bfloat16* pekv  = bp;  bp += (size_t)PE_PAD*512;
    __hip_bfloat16* pe_p  = bp;  bp += (size_t)PE_PAD*DD;
    __hip_bfloat16* inw_p = bp;  bp += (size_t)2*768*DD;
    unsigned* owt2 = (unsigned*)bp;  bp += (size_t)2*DD*DD;   // 2*128*256 dwords
    __hip_bfloat16* l1w_p = bp;  bp += (size_t)2*FFN_*DD;
    __hip_bfloat16* l2w_p = bp;  bp += (size_t)2*DD*FFN_;

    dim3 blk(256);
    auto GG = [](int M, int Nc){ return dim3((unsigned)((((M+31)>>5)*(Nc>>5) + 3) / 4)); };
    const unsigned SK256 = (ROWS/16) * (256 >> 5);    // 151*8 = 1208 blocks
    const unsigned SQKG  = (16*8*100 + 3) / 4;        // 3200 blocks

    // ---- build_x + all weight packs, one dispatch ----
    buildpack_kernel<<<ROWS + PACK_BLOCKS, blk, 0, stream>>>(
        spectra, latent, int_w, pe, x, xb, xqb, masses, maskf,
        in_w, inw_p, out_w, owt2, l1_w, l1w_p, l2_w, l2w_p, pe_p);

    // merged: PEK|PEV GEMM + L0 QKV projection (independent)
    pekv_qkv0_kernel<<<PEKV_BLK + QKV0_BLK, blk, 0, stream>>>(
        pe_p, inw_p + 256*DD, pekv, xqb, xb, inw_p, in_b, qb, kvb);

    // ---------------- layer 0 ----------------
    gemm_sqk<256,512><<<SQKG, blk, 0, stream>>>(qb, kvb, sqkb);
    attn_kernel<true,256,512><<<ROWS, blk, 0, stream>>>(
        qb, kvb + 256, pekv, sqkb, masses, maskf,
        owt2, out_b, x, n1_g, n1_b, x, xb);
    gemm_mfma<__hip_bfloat16><<<GG(ROWS, 1024), blk, 0, stream>>>(
        xb, l1w_p, l1_b, f1b, ROWS, 1024, 256, 1024, 1);
    gemm_skinny<1024><<<SK256, blk, 0, stream>>>(
        f1b, l2w_p, l2_b, y2, ROWS, 256, 256);
    add_ln_kernel<true><<<ROWS, blk, 0, stream>>>(x, y2, n2_g, n2_b, x, xb);

    // ---------------- layer 1 ----------------
    gemm_mfma<__hip_bfloat16><<<GG(ROWS, 768), blk, 0, stream>>>(
        xb, inw_p + 768*DD, in_b + 768, kvb, ROWS, 768, 256, 768, 0);
    gemm_sqk<768,768><<<SQKG, blk, 0, stream>>>(kvb, kvb + 256, sqkb);
    attn_kernel<false,768,768><<<ROWS, blk, 0, stream>>>(
        kvb, kvb + 512, nullptr, sqkb, masses, maskf,
        owt2 + (size_t)128*256, out_b + 256, x, n1_g + 256, n1_b + 256, x, xb);
    gemm_mfma<__hip_bfloat16><<<GG(ROWS, 1024), blk, 0, stream>>>(
        xb, l1w_p + FFN_*DD, l1_b + 1024, f1b, ROWS, 1024, 256, 1024, 1);
    gemm_skinny<1024><<<SK256, blk, 0, stream>>>(
        f1b, l2w_p + DD*FFN_, l2_b + 256, y2, ROWS, 256, 256);
    add_ln_kernel<false><<<ROWS, blk, 0, stream>>>(x, y2, n2_g + 256, n2_b + 256,
                                                   (float*)d_out, nullptr);
}

// Round 12
// 297.609 us; speedup vs baseline: 1.2236x; 1.0174x over previous
//
#include <hip/hip_runtime.h>
#include <hip/hip_bf16.h>
#include <math.h>

// Problem constants
#define BB 16
#define NP 150
#define NN 151          // N = Np + 1
#define DD 256
#define HH 8
#define HD 32
#define FFN_ 1024
#define PE_LEN 20200
#define ROWS (BB*NN)    // 2416
#define MPAD 2432       // ROWS padded to 32
#define PE_PAD 20224    // PE_LEN padded to 32
#define SQS 160         // Sqk padded row (151->160)

// r21: score distribution (302.8us). r22: fused attn+outproj+LN regressed
// via uncoalesced W (364us). r23: transposed dword-paired out_w fixed it
// (302.8us, tie; fusion kept). r24: the three wide GEMMs (FFN-up x2
// Nc=1024, L1 QKV Nc=768) still run 32x32-per-wave gemm_mfma (MfmaUtil~4%,
// latency-bound 8-step serial K-chains). gemm_skinny32: one 32x32 tile per
// BLOCK (W traffic == gemm_mfma, fixing r20's skinny-16 mistake), K split
// across 4 waves (chain 8->2) + LDS partial reduce red[4][16][65]
// (conflict-free, 16.6KB). Blocks x4 (2432/1824) -> TLP hides latency.
// Numerics: f32 partial-K regrouping only (accepted class, r17).
// Index semantics: pe0 idx = 10100; rel-bucket clips -> 100 / 20100.

typedef __attribute__((ext_vector_type(8))) short short8;   // 8 bf16 = 4 VGPR
typedef __attribute__((ext_vector_type(4))) float f32x4;
typedef __attribute__((ext_vector_type(4))) unsigned u32x4; // 4 dwords

#if defined(__has_builtin)
#if __has_builtin(__builtin_amdgcn_fdot2_f32_bf16)
#define HAVE_DOT2 1
#endif
#endif
#ifndef HAVE_DOT2
#define HAVE_DOT2 0
#endif

__device__ __forceinline__ float r16(float x) {
    return __bfloat162float(__float2bfloat16(x));   // RNE bf16 grid
}
__device__ __forceinline__ float us2f(unsigned short u) {
    return __uint_as_float((unsigned)u << 16);      // bf16 bits -> f32
}
__device__ __forceinline__ float lo2f(unsigned x) {
    return __uint_as_float(x << 16);                // low bf16 of dword
}
__device__ __forceinline__ float hi2f(unsigned x) {
    return __uint_as_float(x & 0xFFFF0000u);        // high bf16 of dword
}
__device__ __forceinline__ unsigned short f2us(float x) {
    __hip_bfloat16 h = __float2bfloat16(x);
    return *reinterpret_cast<unsigned short*>(&h);  // RNE bf16 bits
}
__device__ __forceinline__ unsigned cvtpk(float lo, float hi) {
    unsigned r;                                     // D.lo=bf16(lo) D.hi=bf16(hi), RNE
    asm("v_cvt_pk_bf16_f32 %0, %1, %2" : "=v"(r) : "v"(lo), "v"(hi));
    return r;
}
#if HAVE_DOT2
typedef __attribute__((ext_vector_type(2))) __bf16 bf16x2;
__device__ __forceinline__ float dot2bf(unsigned a, unsigned b, float acc) {
    bf16x2 av = __builtin_bit_cast(bf16x2, a);
    bf16x2 bv = __builtin_bit_cast(bf16x2, b);
    return __builtin_amdgcn_fdot2_f32_bf16(av, bv, acc, false);
}
#endif

// ---------------------------------------------------------------------------
// build_x (+ fused weight packs on trailing blocks).
// owt2: out_w transposed dword-pair pack.
// ---------------------------------------------------------------------------
#define PACK_BLOCKS 1024
__global__ __launch_bounds__(256) void buildpack_kernel(
    const float* __restrict__ spectra, const float* __restrict__ latent,
    const float* __restrict__ int_w, const float* __restrict__ pe,
    float* __restrict__ x, __hip_bfloat16* __restrict__ xb,
    __hip_bfloat16* __restrict__ xqb,
    float* __restrict__ masses, float* __restrict__ maskf,
    const float* __restrict__ in_w,  __hip_bfloat16* __restrict__ inw_p,
    const float* __restrict__ out_w, unsigned* __restrict__ owt2,
    const float* __restrict__ l1_w,  __hip_bfloat16* __restrict__ l1w_p,
    const float* __restrict__ l2_w,  __hip_bfloat16* __restrict__ l2w_p,
    __hip_bfloat16* __restrict__ pe_p)
{
    int tid = threadIdx.x;
    if (blockIdx.x < ROWS) {
        int bn = blockIdx.x;            // b*NN + n
        int b = bn / NN, n = bn % NN;
        float val;
        if (n == 0) {
            val = latent[tid];
            if (tid == 0) { masses[bn] = 0.0f; maskf[bn] = 0.0f; }
        } else {
            float mz = spectra[(b*NP + n - 1)*2 + 0];
            float it = spectra[(b*NP + n - 1)*2 + 1];
            int i = (tid < 128) ? tid : tid - 128;
            const double base_d = 0.001 / (2.0 * 3.141592653589793);
            double term_d = base_d * pow(1.0e7, (double)i / 127.0);
            float tf = (float)term_d;                   // .astype(np.float32)
            double arg = (double)mz / (double)tf;
            double sv = (tid < 128) ? sin(arg) : cos(arg);
            val = (float)sv + it * int_w[tid];
            if (tid == 0) {
                masses[bn] = mz;
                maskf[bn] = ((mz + it) == 0.0f) ? 1.0f : 0.0f;
            }
        }
        x[bn*DD + tid] = val;
        xb[bn*DD + tid] = __float2bfloat16(val);
        xqb[bn*DD + tid] = __float2bfloat16(val + pe[10100*DD + tid]);
    } else {
        long long base = (long long)(blockIdx.x - ROWS) * 256 + tid;
        const long long stride = (long long)PACK_BLOCKS * 256;
        for (long long i = base; i < (long long)PE_PAD*DD; i += stride)
            pe_p[i] = __float2bfloat16(i < (long long)PE_LEN*DD ? pe[i] : 0.0f);
        for (long long i = base; i < 2LL*768*DD; i += stride)
            inw_p[i] = __float2bfloat16(in_w[i]);
        for (long long i = base; i < 2LL*128*256; i += stride) {
            long long l = i / (128*256), rem = i % (128*256);
            long long k2 = rem / 256, gc = rem % 256;
            const float* src = out_w + l*DD*DD + gc*DD + 2*k2;
            owt2[i] = (unsigned)f2us(src[0]) | ((unsigned)f2us(src[1]) << 16);
        }
        for (long long i = base; i < 2LL*FFN_*DD; i += stride)
            l1w_p[i] = __float2bfloat16(l1_w[i]);
        for (long long i = base; i < 2LL*DD*FFN_; i += stride)
            l2w_p[i] = __float2bfloat16(l2_w[i]);
    }
}

// ---------------------------------------------------------------------------
// Skinny32 GEMM (wide-Nc ROWS GEMMs): one 32x32 tile per BLOCK, K split
// across the 4 waves (K/4 each; chain 8->2 for K=256), LDS partial reduce
// red[4][16][65] (pad -> conflict-free), distributed epilogue
// r16(r16(sum)+r16(bias)) [+relu]. W traffic identical to gemm_mfma.
// Grid = (M/32)*(Nc/32) blocks.
// ---------------------------------------------------------------------------
template<int K, typename CT, int RELU>
__global__ __launch_bounds__(256) void gemm_skinny32(
    const __hip_bfloat16* __restrict__ A, const __hip_bfloat16* __restrict__ W,
    const float* __restrict__ bias, CT* __restrict__ C,
    int M, int Nc, int ldc)
{
    int NT = Nc >> 5;
    int mt = blockIdx.x / NT, nt = blockIdx.x % NT;
    int m0 = mt * 32, n0 = nt * 32;
    int wave = threadIdx.x >> 6;
    int lane = threadIdx.x & 63;
    int rl = lane & 15, q8 = (lane >> 4) * 8;
    const int K4 = K >> 2;              // K slice per wave
    int k0 = wave * K4;

    const short8* Ap0 = (const short8*)(A + (size_t)(m0 + rl)*K + k0 + q8);
    const short8* Ap1 = (const short8*)(A + (size_t)(m0 + 16 + rl)*K + k0 + q8);
    const short8* Wp0 = (const short8*)(W + (size_t)(n0 + rl)*K + k0 + q8);
    const short8* Wp1 = (const short8*)(W + (size_t)(n0 + 16 + rl)*K + k0 + q8);

    f32x4 acc00 = {0,0,0,0}, acc01 = {0,0,0,0};
    f32x4 acc10 = {0,0,0,0}, acc11 = {0,0,0,0};
    #pragma unroll
    for (int s = 0; s < K4/32; ++s) {
        short8 a0 = Ap0[s*4];
        short8 a1 = Ap1[s*4];
        short8 b0 = Wp0[s*4];
        short8 b1 = Wp1[s*4];
        acc00 = __builtin_amdgcn_mfma_f32_16x16x32_bf16(a0, b0, acc00, 0, 0, 0);
        acc01 = __builtin_amdgcn_mfma_f32_16x16x32_bf16(a0, b1, acc01, 0, 0, 0);
        acc10 = __builtin_amdgcn_mfma_f32_16x16x32_bf16(a1, b0, acc10, 0, 0, 0);
        acc11 = __builtin_amdgcn_mfma_f32_16x16x32_bf16(a1, b1, acc11, 0, 0, 0);
    }

    // slots: sl = sm*8 + sn*4 + rg  (sm,sn in {0,1}, rg in 0..3)
    __shared__ float red[4][16][65];
    #pragma unroll
    for (int rg = 0; rg < 4; ++rg) {
        red[wave][0*8 + 0*4 + rg][lane] = acc00[rg];
        red[wave][0*8 + 1*4 + rg][lane] = acc01[rg];
        red[wave][1*8 + 0*4 + rg][lane] = acc10[rg];
        red[wave][1*8 + 1*4 + rg][lane] = acc11[rg];
    }
    __syncthreads();

    #pragma unroll
    for (int t = 0; t < 4; ++t) {
        int sl = wave*4 + t;
        float s = red[0][sl][lane] + red[1][sl][lane]
                + red[2][sl][lane] + red[3][sl][lane];
        int rg = sl & 3, sn = (sl >> 2) & 1, sm = sl >> 3;
        int gr = m0 + sm*16 + (lane >> 4)*4 + rg;
        int gc = n0 + sn*16 + rl;
        float val = r16(s);
        val = r16(val + r16(bias[gc]));
        if (RELU) val = fmaxf(val, 0.0f);
        if (gr < M) C[(size_t)gr*ldc + gc] = (CT)val;
    }
}

// ---------------------------------------------------------------------------
// Skinny GEMM for Nc=256 (FFN-down): one 16x32 tile per BLOCK, K split
// across the 4 waves, LDS partial reduce, distributed epilogue.
// ---------------------------------------------------------------------------
template<int K>
__global__ __launch_bounds__(256) void gemm_skinny(
    const __hip_bfloat16* __restrict__ A, const __hip_bfloat16* __restrict__ W,
    const float* __restrict__ bias, float* __restrict__ C,
    int M, int Nc, int ldc)
{
    int NT = Nc >> 5;
    int id = blockIdx.x;
    int mt = id / NT, nt = id % NT;
    int m0 = mt * 16, n0 = nt * 32;
    int wave = threadIdx.x >> 6;
    int lane = threadIdx.x & 63;
    int rl = lane & 15, q8 = (lane >> 4) * 8;
    const int K4 = K >> 2;              // K slice per wave
    int k0 = wave * K4;

    const short8* Ap  = (const short8*)(A + (size_t)(m0 + rl)*K + k0 + q8);
    const short8* Wp0 = (const short8*)(W + (size_t)(n0 + rl)*K + k0 + q8);
    const short8* Wp1 = (const short8*)(W + (size_t)(n0 + 16 + rl)*K + k0 + q8);

    f32x4 acc0 = {0,0,0,0}, acc1 = {0,0,0,0};
    #pragma unroll
    for (int s = 0; s < K4/32; ++s) {
        short8 a  = Ap[s*4];
        short8 b0 = Wp0[s*4];
        short8 b1 = Wp1[s*4];
        acc0 = __builtin_amdgcn_mfma_f32_16x16x32_bf16(a, b0, acc0, 0, 0, 0);
        acc1 = __builtin_amdgcn_mfma_f32_16x16x32_bf16(a, b1, acc1, 0, 0, 0);
    }

    __shared__ float red[4][8][65];     // [wave][slot][lane] pad->no conflicts
    #pragma unroll
    for (int rg = 0; rg < 4; ++rg) {
        red[wave][rg][lane]   = acc0[rg];
        red[wave][4+rg][lane] = acc1[rg];
    }
    __syncthreads();

    #pragma unroll
    for (int t = 0; t < 2; ++t) {
        int sl = wave*2 + t;
        float s = red[0][sl][lane] + red[1][sl][lane]
                + red[2][sl][lane] + red[3][sl][lane];
        int rg = sl & 3, sn = sl >> 2;
        int gr = m0 + (lane >> 4)*4 + rg;
        int gc = n0 + sn*16 + rl;
        float val = r16(s);
        val = r16(val + r16(bias[gc]));
        if (gr < M) C[(size_t)gr*ldc + gc] = val;
    }
}

// ---------------------------------------------------------------------------
// Batched score GEMM: Sqk[b][h][i][j] = sum_d Q[b,i,h*32+d] * K[b,j,h*32+d],
// f32, unscaled, unmasked. One 16x16 (i x j) tile per wave, K=32 = 1 MFMA.
// ---------------------------------------------------------------------------
template<int QS, int KS>
__global__ __launch_bounds__(256) void gemm_sqk(
    const __hip_bfloat16* __restrict__ Q, const __hip_bfloat16* __restrict__ Kp,
    float* __restrict__ S)
{
    int wave = threadIdx.x >> 6;
    int lane = threadIdx.x & 63;
    int id = blockIdx.x * 4 + wave;         // b(16) x h(8) x it(10) x jt(10)
    if (id >= 16*8*100) return;
    int jt = id % 10, it = (id / 10) % 10;
    int h = (id / 100) & 7, b = id / 800;
    int i0 = it * 16, j0 = jt * 16;
    int rl = lane & 15, q8 = (lane >> 4) * 8;

    short8 a  = *(const short8*)(Q  + (size_t)(b*NN + i0 + rl)*QS + h*32 + q8);
    short8 kb = *(const short8*)(Kp + (size_t)(b*NN + j0 + rl)*KS + h*32 + q8);
    f32x4 acc = {0,0,0,0};
    acc = __builtin_amdgcn_mfma_f32_16x16x32_bf16(a, kb, acc, 0, 0, 0);

    float* Sb = S + ((size_t)(b*8 + h))*SQS*SQS;
    int rbase = (lane >> 4) * 4;
    #pragma unroll
    for (int rg = 0; rg < 4; ++rg) {
        int ii = i0 + rbase + rg, jj = j0 + rl;
        if (ii < NN && jj < NN)
            Sb[(size_t)ii*SQS + jj] = acc[rg];
    }
}

// ---------------------------------------------------------------------------
// Merged pekv GEMM + L0 QKV projection (independent, both read weight packs).
// ---------------------------------------------------------------------------
#define PEKV_BLK 632u   // ceil(158*16 tiles / 4 waves)
#define QKV0_BLK 456u   // ceil(76*24 tiles / 4 waves)

__device__ __forceinline__ void pekv_body(
    unsigned bid, int wave, int lane,
    const __hip_bfloat16* __restrict__ A, const __hip_bfloat16* __restrict__ W,
    __hip_bfloat16* __restrict__ C)
{
    const int K = 256, Nc = 512, ldc = 512, M = PE_LEN;
    int NT = Nc >> 5;
    int MT4 = (M + 127) >> 7;
    int id = bid * 4 + wave;
    if (id >= MT4 * NT) return;
    int mt = id / NT, nt = id % NT;
    int m0 = mt * 128, n0 = nt * 32;
    int rl = lane & 15, q8 = (lane >> 4) * 8;

    const short8* Ab  = (const short8*)(A + (size_t)(m0 + rl)*K + q8);
    const short8* Wp0 = (const short8*)(W + (size_t)(n0 + rl)*K + q8);
    const short8* Wp1 = (const short8*)(W + (size_t)(n0 + 16 + rl)*K + q8);
    const int rstep = K >> 3;                  // short8 units per row

    f32x4 acc[4][2][2] = {};
    for (int s = 0; s < 8; ++s) {              // K/32 = 8
        short8 b0 = Wp0[s*4];
        short8 b1 = Wp1[s*4];
        short8 a[4][2];
        #pragma unroll
        for (int t = 0; t < 4; ++t) {
            a[t][0] = Ab[(size_t)(t*32)*rstep + s*4];
            a[t][1] = Ab[(size_t)(t*32+16)*rstep + s*4];
        }
        #pragma unroll
        for (int t = 0; t < 4; ++t) {
            acc[t][0][0] = __builtin_amdgcn_mfma_f32_16x16x32_bf16(a[t][0], b0, acc[t][0][0], 0, 0, 0);
            acc[t][0][1] = __builtin_amdgcn_mfma_f32_16x16x32_bf16(a[t][0], b1, acc[t][0][1], 0, 0, 0);
            acc[t][1][0] = __builtin_amdgcn_mfma_f32_16x16x32_bf16(a[t][1], b0, acc[t][1][0], 0, 0, 0);
            acc[t][1][1] = __builtin_amdgcn_mfma_f32_16x16x32_bf16(a[t][1], b1, acc[t][1][1], 0, 0, 0);
        }
    }

    int rbase = (lane >> 4) * 4;
    #pragma unroll
    for (int t = 0; t < 4; ++t) {
        #pragma unroll
        for (int sm = 0; sm < 2; ++sm) {
            #pragma unroll
            for (int sn = 0; sn < 2; ++sn) {
                f32x4 a = acc[t][sm][sn];
                int gc = n0 + sn*16 + rl;
                #pragma unroll
                for (int rg = 0; rg < 4; ++rg) {
                    int gr = m0 + t*32 + sm*16 + rbase + rg;
                    if (gr < M)
                        C[(size_t)gr*ldc + gc] = (__hip_bfloat16)r16(a[rg]);
                }
            }
        }
    }
}

__device__ __forceinline__ void qkv0_body(
    unsigned bid, int wave, int lane,
    const __hip_bfloat16* __restrict__ xqb, const __hip_bfloat16* __restrict__ xb,
    const __hip_bfloat16* __restrict__ inw_p, const float* __restrict__ in_b,
    __hip_bfloat16* __restrict__ qb, __hip_bfloat16* __restrict__ kvb, int M)
{
    int MT = (M + 31) >> 5;
    int id = bid * 4 + wave;
    if (id >= MT * 24) return;
    int mt = id / 24, ntt = id % 24;
    bool isQ = (ntt < 8);
    const __hip_bfloat16* A = isQ ? xqb : xb;
    const __hip_bfloat16* W = inw_p + (isQ ? (size_t)ntt*32*DD
                                           : (size_t)(256 + (ntt-8)*32)*DD);
    const float* bias = in_b + (isQ ? ntt*32 : 256 + (ntt-8)*32);
    __hip_bfloat16* C = isQ ? qb : kvb;
    int ldc = isQ ? 256 : 512;
    int cbase = isQ ? ntt*32 : (ntt-8)*32;
    int m0 = mt * 32;
    int rl = lane & 15, q8 = (lane >> 4) * 8;
    const int K = DD;

    const short8* Ap0 = (const short8*)(A + (size_t)(m0 + rl)*K + q8);
    const short8* Ap1 = (const short8*)(A + (size_t)(m0 + 16 + rl)*K + q8);
    const short8* Wp0 = (const short8*)(W + (size_t)(rl)*K + q8);
    const short8* Wp1 = (const short8*)(W + (size_t)(16 + rl)*K + q8);

    f32x4 acc00 = {0,0,0,0}, acc01 = {0,0,0,0};
    f32x4 acc10 = {0,0,0,0}, acc11 = {0,0,0,0};
    for (int s = 0; s < K/32; ++s) {
        short8 a0 = Ap0[s*4];
        short8 a1 = Ap1[s*4];
        short8 b0 = Wp0[s*4];
        short8 b1 = Wp1[s*4];
        acc00 = __builtin_amdgcn_mfma_f32_16x16x32_bf16(a0, b0, acc00, 0, 0, 0);
        acc01 = __builtin_amdgcn_mfma_f32_16x16x32_bf16(a0, b1, acc01, 0, 0, 0);
        acc10 = __builtin_amdgcn_mfma_f32_16x16x32_bf16(a1, b0, acc10, 0, 0, 0);
        acc11 = __builtin_amdgcn_mfma_f32_16x16x32_bf16(a1, b1, acc11, 0, 0, 0);
    }

    int rbase = (lane >> 4) * 4;
    #pragma unroll
    for (int sm = 0; sm < 2; ++sm) {
        #pragma unroll
        for (int sn = 0; sn < 2; ++sn) {
            f32x4 a = (sm == 0) ? (sn == 0 ? acc00 : acc01)
                                : (sn == 0 ? acc10 : acc11);
            int gc = cbase + sn*16 + rl;
            float bv = r16(bias[sn*16 + rl]);
            #pragma unroll
            for (int rg = 0; rg < 4; ++rg) {
                int gr = m0 + sm*16 + rbase + rg;
                if (gr < M) {
                    float val = r16(a[rg]);
                    val = r16(val + bv);
                    C[(size_t)gr*ldc + gc] = (__hip_bfloat16)val;
                }
            }
        }
    }
}

__global__ __launch_bounds__(256) void pekv_qkv0_kernel(
    const __hip_bfloat16* __restrict__ pe_p, const __hip_bfloat16* __restrict__ wkv0,
    __hip_bfloat16* __restrict__ pekv,
    const __hip_bfloat16* __restrict__ xqb, const __hip_bfloat16* __restrict__ xb,
    const __hip_bfloat16* __restrict__ inw_p, const float* __restrict__ in_b,
    __hip_bfloat16* __restrict__ qb, __hip_bfloat16* __restrict__ kvb)
{
    int wave = threadIdx.x >> 6;
    int lane = threadIdx.x & 63;
    if (blockIdx.x < PEKV_BLK)
        pekv_body(blockIdx.x, wave, lane, pe_p, wkv0, pekv);
    else
        qkv0_body(blockIdx.x - PEKV_BLK, wave, lane, xqb, xb, inw_p, in_b,
                  qb, kvb, ROWS);
}

// ---------------------------------------------------------------------------
// Fused attention + out-proj + residual + layernorm. One block per (b,i),
// b = blk&15 (XCD locality). Thread (g = tid>>5, c = tid&31).
// Scores: Sqk preload; USE_PE adds PE-gather dot (Phase A). Phase B as r21.
// Epilogue: y row -> bf16 pairs (ypk, LDS broadcast) -> per-thread 256-dot
// vs TRANSPOSED dword-paired out_w (WT[k2*256+tid]: coalesced) ->
// r16(r16(dot)+r16(bias)) -> residual -> LN -> xout/xbout.
// ---------------------------------------------------------------------------
template<bool USE_PE, int QS, int VS>
__global__ __launch_bounds__(256) void attn_kernel(
    const __hip_bfloat16* __restrict__ qp,
    const __hip_bfloat16* __restrict__ vp,
    const __hip_bfloat16* __restrict__ pekv,
    const float* __restrict__ sqk,
    const float* __restrict__ masses, const float* __restrict__ maskf,
    const unsigned* __restrict__ outwT, const float* __restrict__ outb,
    const float* __restrict__ xres,
    const float* __restrict__ lng, const float* __restrict__ lnb,
    float* __restrict__ xout, __hip_bfloat16* __restrict__ xbout)
{
    int b = blockIdx.x & 15;        // XCD-locality swizzle (pure permutation)
    int i = blockIdx.x >> 4;
    int tid = threadIdx.x;
    int c = tid & 31;               // 8-column chunk index
    int g = tid >> 5;               // row-residue class
    int h = c >> 2;                 // head owning columns c*8..c*8+7
    const float scale = 0.17677669529663687f;   // 1/sqrt(32)

    __shared__ float sc[HH][152];
    __shared__ float msh[152];
    __shared__ int   tj[152];
    __shared__ __align__(16) float part[8][264];
    __shared__ float yrow[256];
    __shared__ unsigned ypk[128];
    __shared__ float red2[4];

    if (tid < NN) {
        float mval = maskf[b*NN + tid];
        msh[tid] = mval;
        if (USE_PE) {
            double m = (double)masses[b*NN + tid] - (double)masses[b*NN + i];
            m = fmin(fmax(m, -100.0), 100.0);
            tj[tid] = (int)(((m + 1.0) + 100.0) / 0.01);  // f64: clips 100/20100
        }
        // preload Sqk rows (coalesced in j)
        const float* Sb = sqk + ((size_t)(b*8))*SQS*SQS + (size_t)i*SQS + tid;
        if (USE_PE) {
            #pragma unroll
            for (int hh = 0; hh < 8; ++hh)
                sc[hh][tid] = Sb[(size_t)hh*SQS*SQS];     // raw; PE+scale+mask in Phase A
        } else {
            #pragma unroll
            for (int hh = 0; hh < 8; ++hh) {
                float s = Sb[(size_t)hh*SQS*SQS] * scale;
                sc[hh][tid] = (mval != 0.0f) ? -1e9f : s;
            }
        }
    }

    // preload Q chunk (only needed for the PE dot)
    unsigned qw[4];
#if !HAVE_DOT2
    float qf[8];
#endif
    if (USE_PE) {
        const u32x4 q4 = *(const u32x4*)((const unsigned short*)qp
                            + (size_t)(b*NN + i)*QS + c*8);
        qw[0] = q4[0]; qw[1] = q4[1]; qw[2] = q4[2]; qw[3] = q4[3];
#if !HAVE_DOT2
        #pragma unroll
        for (int w = 0; w < 4; ++w) { qf[2*w] = lo2f(qw[w]); qf[2*w+1] = hi2f(qw[w]); }
#endif
    }
    __syncthreads();

    const unsigned short* vbase = (const unsigned short*)vp + (size_t)(b*NN)*VS + c*8;
    const unsigned short* pkb = (const unsigned short*)pekv + c*8;        // PEK col
    const unsigned short* pvb = (const unsigned short*)pekv + 256 + c*8;  // PEV col

    // ---- Phase A (USE_PE only): PE-gather dot added to preloaded Sqk ----
    if (USE_PE) {
        int j = g;
        u32x4 pcur = *(const u32x4*)(pkb + (size_t)tj[j]*512);
        for (int p = 0; p < 19; ++p) {
            int jn = j + 8;
            bool more = (jn < NN);
            u32x4 pn;
            if (more) pn = *(const u32x4*)(pkb + (size_t)tj[jn]*512);
            float acc = 0.0f;
#if HAVE_DOT2
            #pragma unroll
            for (int w = 0; w < 4; ++w) acc = dot2bf(qw[w], pcur[w], acc);
#else
            #pragma unroll
            for (int w = 0; w < 4; ++w) {
                acc = fmaf(qf[2*w],   lo2f(pcur[w]), acc);
                acc = fmaf(qf[2*w+1], hi2f(pcur[w]), acc);
            }
#endif
            acc += __shfl_xor(acc, 1);
            acc += __shfl_xor(acc, 2);
            if ((c & 3) == 0) {
                float s = (sc[h][j] + acc) * scale;
                if (msh[j] != 0.0f) s = -1e9f;
                sc[h][j] = s;
            }
            if (!more) break;
            j = jn; pcur = pn;
        }
        __syncthreads();
    }

    // ---- softmax per head, f32, within 32-lane group (head = g) ----
    {
        int lane = tid & 31;
        int hh = g;
        float mx = -INFINITY;
        for (int j = lane; j < NN; j += 32) mx = fmaxf(mx, sc[hh][j]);
        #pragma unroll
        for (int off = 16; off; off >>= 1) mx = fmaxf(mx, __shfl_xor(mx, off, 32));
        float sum = 0.0f;
        for (int j = lane; j < NN; j += 32) {
            float e = expf(sc[hh][j] - mx);
            sc[hh][j] = e;
            sum += e;
        }
        #pragma unroll
        for (int off = 16; off; off >>= 1) sum += __shfl_xor(sum, off, 32);
        float inv = 1.0f / sum;
        for (int j = lane; j < NN; j += 32) sc[hh][j] = r16(sc[hh][j] * inv); // bf16(a)
    }
    __syncthreads();

    // ---- Phase B: partial y over row class, then cross-group reduce ----
    {
        float ya[8];
        #pragma unroll
        for (int u = 0; u < 8; ++u) ya[u] = 0.0f;

#if HAVE_DOT2
        // rows paired (jA = g+16t, jB = jA+8), t = 0..8; tail row g+144 if valid
        u32x4 vA = *(const u32x4*)(vbase + (size_t)g*VS);
        u32x4 vB = *(const u32x4*)(vbase + (size_t)(g+8)*VS);
        u32x4 pA, pB;
        if (USE_PE) {
            pA = *(const u32x4*)(pvb + (size_t)tj[g]*512);
            pB = *(const u32x4*)(pvb + (size_t)tj[g+8]*512);
        }
        for (int t = 0; t < 9; ++t) {
            int jA = g + t*16, jB = jA + 8;
            u32x4 nvA, nvB, npA, npB;
            if (t < 8) {
                int nA = jA + 16, nB = jB + 16;
                nvA = *(const u32x4*)(vbase + (size_t)nA*VS);
                nvB = *(const u32x4*)(vbase + (size_t)nB*VS);
                if (USE_PE) {
                    npA = *(const u32x4*)(pvb + (size_t)tj[nA]*512);
                    npB = *(const u32x4*)(pvb + (size_t)tj[nB]*512);
                }
            }
            unsigned apair = cvtpk(sc[h][jA], sc[h][jB]);   // lo=aA hi=aB
            #pragma unroll
            for (int w = 0; w < 4; ++w) {
                unsigned lopair, hipair;
                if (USE_PE) {
                    float sA0 = lo2f(vA[w]) + lo2f(pA[w]);
                    float sA1 = hi2f(vA[w]) + hi2f(pA[w]);
                    float sB0 = lo2f(vB[w]) + lo2f(pB[w]);
                    float sB1 = hi2f(vB[w]) + hi2f(pB[w]);
                    lopair = cvtpk(sA0, sB0);
                    hipair = cvtpk(sA1, sB1);
                } else {
                    lopair = __builtin_amdgcn_perm(vB[w], vA[w], 0x05040100u);
                    hipair = __builtin_amdgcn_perm(vB[w], vA[w], 0x07060302u);
                }
                ya[2*w]   = dot2bf(apair, lopair, ya[2*w]);
                ya[2*w+1] = dot2bf(apair, hipair, ya[2*w+1]);
            }
            if (t < 8) {
                vA = nvA; vB = nvB;
                if (USE_PE) { pA = npA; pB = npB; }
            }
        }
        if (g + 144 < NN) {                 // tail row (g < 7)
            int jT = g + 144;
            u32x4 v = *(const u32x4*)(vbase + (size_t)jT*VS);
            u32x4 pq;
            if (USE_PE) pq = *(const u32x4*)(pvb + (size_t)tj[jT]*512);
            float aT = sc[h][jT];
            #pragma unroll
            for (int w = 0; w < 4; ++w) {
                float v0 = lo2f(v[w]), v1 = hi2f(v[w]);
                if (USE_PE) {
                    unsigned pk2 = cvtpk(v0 + lo2f(pq[w]), v1 + hi2f(pq[w]));
                    v0 = lo2f(pk2); v1 = hi2f(pk2);
                }
                ya[2*w]   = fmaf(aT, v0, ya[2*w]);
                ya[2*w+1] = fmaf(aT, v1, ya[2*w+1]);
            }
        }
#else
        int j = g;
        u32x4 vcur = *(const u32x4*)(vbase + (size_t)j*VS);
        u32x4 pcur;
        if (USE_PE) pcur = *(const u32x4*)(pvb + (size_t)tj[j]*512);
        float acur = sc[h][j];
        for (int p = 0; p < 19; ++p) {
            int jn = j + 8;
            bool more = (jn < NN);
            u32x4 vn, pn;
            float an = 0.0f;
            if (more) {
                vn = *(const u32x4*)(vbase + (size_t)jn*VS);
                if (USE_PE) pn = *(const u32x4*)(pvb + (size_t)tj[jn]*512);
                an = sc[h][jn];
            }
            #pragma unroll
            for (int w = 0; w < 4; ++w) {
                float v0 = lo2f(vcur[w]), v1 = hi2f(vcur[w]);
                if (USE_PE) {
                    v0 = r16(v0 + lo2f(pcur[w]));
                    v1 = r16(v1 + hi2f(pcur[w]));
                }
                ya[2*w]   = fmaf(acur, v0, ya[2*w]);
                ya[2*w+1] = fmaf(acur, v1, ya[2*w+1]);
            }
            if (!more) break;
            j = jn; vcur = vn; acur = an;
            if (USE_PE) pcur = pn;
        }
#endif
        f32x4* pp = (f32x4*)&part[g][c*8];
        pp[0] = f32x4{ya[0], ya[1], ya[2], ya[3]};
        pp[1] = f32x4{ya[4], ya[5], ya[6], ya[7]};
    }
    __syncthreads();

    // ---- fused out-proj + residual + layernorm (row-local) ----
    {
        float s = part[0][tid];
        #pragma unroll
        for (int g2 = 1; g2 < 8; ++g2) s += part[g2][tid];
        yrow[tid] = s;
    }
    __syncthreads();
    if (tid < 128) ypk[tid] = cvtpk(yrow[2*tid], yrow[2*tid + 1]);  // bf16 y operand
    __syncthreads();
    {
        float a0 = 0.0f, a1 = 0.0f, a2 = 0.0f, a3 = 0.0f;
        #pragma unroll
        for (int k2 = 0; k2 < 128; k2 += 4) {
            unsigned w0 = outwT[(size_t)(k2+0)*256 + tid];
            unsigned w1 = outwT[(size_t)(k2+1)*256 + tid];
            unsigned w2 = outwT[(size_t)(k2+2)*256 + tid];
            unsigned w3 = outwT[(size_t)(k2+3)*256 + tid];
#if HAVE_DOT2
            a0 = dot2bf(ypk[k2+0], w0, a0);
            a1 = dot2bf(ypk[k2+1], w1, a1);
            a2 = dot2bf(ypk[k2+2], w2, a2);
            a3 = dot2bf(ypk[k2+3], w3, a3);
#else
            a0 = fmaf(lo2f(ypk[k2+0]), lo2f(w0), a0);
            a1 = fmaf(hi2f(ypk[k2+0]), hi2f(w0), a1);
            a2 = fmaf(lo2f(ypk[k2+1]), lo2f(w1), a2);
            a3 = fmaf(hi2f(ypk[k2+1]), hi2f(w1), a3);
            a0 = fmaf(lo2f(ypk[k2+2]), lo2f(w2), a0);
            a1 = fmaf(hi2f(ypk[k2+2]), hi2f(w2), a1);
            a2 = fmaf(lo2f(ypk[k2+3]), lo2f(w3), a2);
            a3 = fmaf(hi2f(ypk[k2+3]), hi2f(w3), a3);
#endif
        }
        float val = r16((a0 + a1) + (a2 + a3));
        val = r16(val + r16(outb[tid]));
        size_t row = (size_t)(b*NN + i)*DD + tid;
        float v = xres[row] + val;

        float sr = v;
        #pragma unroll
        for (int off = 32; off; off >>= 1) sr += __shfl_xor(sr, off);
        if ((tid & 63) == 0) red2[tid >> 6] = sr;
        __syncthreads();
        float mu = (red2[0] + red2[1] + red2[2] + red2[3]) * (1.0f/256.0f);
        __syncthreads();
        float dd = v - mu;
        float s2 = dd*dd;
        #pragma unroll
        for (int off = 32; off; off >>= 1) s2 += __shfl_xor(s2, off);
        if ((tid & 63) == 0) red2[tid >> 6] = s2;
        __syncthreads();
        float var = (red2[0] + red2[1] + red2[2] + red2[3]) * (1.0f/256.0f);
        float out = dd * (1.0f / sqrtf(var + 1e-5f)) * lng[tid] + lnb[tid];
        xout[row] = out;
        xbout[row] = __float2bfloat16(out);
    }
}

// ---------------------------------------------------------------------------
// add + layernorm, one block per row (f32). Optionally writes bf16 shadow.
// ---------------------------------------------------------------------------
template<bool WRITE_B>
__global__ __launch_bounds__(256) void add_ln_kernel(
    const float* __restrict__ xin, const float* __restrict__ res,
    const float* __restrict__ g, const float* __restrict__ bb,
    float* __restrict__ xout, __hip_bfloat16* __restrict__ xbout)
{
    int r = blockIdx.x; int tid = threadIdx.x;
    float v = xin[r*DD + tid] + res[r*DD + tid];
    __shared__ float red[4];
    float s = v;
    #pragma unroll
    for (int off = 32; off; off >>= 1) s += __shfl_xor(s, off);
    if ((tid & 63) == 0) red[tid >> 6] = s;
    __syncthreads();
    float mu = (red[0] + red[1] + red[2] + red[3]) * (1.0f/256.0f);
    __syncthreads();
    float d = v - mu;
    float s2 = d*d;
    #pragma unroll
    for (int off = 32; off; off >>= 1) s2 += __shfl_xor(s2, off);
    if ((tid & 63) == 0) red[tid >> 6] = s2;
    __syncthreads();
    float var = (red[0] + red[1] + red[2] + red[3]) * (1.0f/256.0f);
    float out = d * (1.0f / sqrtf(var + 1e-5f)) * g[tid] + bb[tid];
    xout[r*DD + tid] = out;
    if (WRITE_B) xbout[r*DD + tid] = __float2bfloat16(out);
}

// ---------------------------------------------------------------------------
extern "C" void kernel_launch(void* const* d_in, const int* in_sizes, int n_in,
                              void* d_out, int out_size, void* d_ws, size_t ws_size,
                              hipStream_t stream)
{
    const float* spectra = (const float*)d_in[0];
    const float* pe      = (const float*)d_in[1];
    const float* latent  = (const float*)d_in[2];
    const float* int_w   = (const float*)d_in[3];
    const float* in_w    = (const float*)d_in[4];
    const float* in_b    = (const float*)d_in[5];
    const float* out_w   = (const float*)d_in[6];
    const float* out_b   = (const float*)d_in[7];
    const float* l1_w    = (const float*)d_in[8];
    const float* l1_b    = (const float*)d_in[9];
    const float* l2_w    = (const float*)d_in[10];
    const float* l2_b    = (const float*)d_in[11];
    const float* n1_g    = (const float*)d_in[12];
    const float* n1_b    = (const float*)d_in[13];
    const float* n2_g    = (const float*)d_in[14];
    const float* n2_b    = (const float*)d_in[15];

    // ---- workspace layout ----
    float* x      = (float*)d_ws;                 // ROWS*256
    float* y2     = x      + ROWS*DD;             // ROWS*256
    float* masses = y2     + ROWS*DD;             // ROWS
    float* maskf  = masses + ROWS;                // ROWS
    float* sqkb   = maskf  + ROWS;                // 16*8*SQS*SQS f32 (13.1MB)
    __hip_bfloat16* bp = (__hip_bfloat16*)(sqkb + (size_t)16*8*SQS*SQS);
    __hip_bfloat16* xb    = bp;  bp += (size_t)MPAD*DD;
    __hip_bfloat16* xqb   = bp;  bp += (size_t)MPAD*DD;
    __hip_bfloat16* qb    = bp;  bp += (size_t)MPAD*DD;
    __hip_bfloat16* kvb   = bp;  bp += (size_t)MPAD*768;
    __hip_bfloat16* f1b   = bp;  bp += (size_t)MPAD*FFN_;
    __hip_bfloat16* pekv  = bp;  bp += (size_t)PE_PAD*512;
    __hip_bfloat16* pe_p  = bp;  bp += (size_t)PE_PAD*DD;
    __hip_bfloat16* inw_p = bp;  bp += (size_t)2*768*DD;
    unsigned* owt2 = (unsigned*)bp;  bp += (size_t)2*DD*DD;   // 2*128*256 dwords
    __hip_bfloat16* l1w_p = bp;  bp += (size_t)2*FFN_*DD;
    __hip_bfloat16* l2w_p = bp;  bp += (size_t)2*DD*FFN_;

    dim3 blk(256);
    const unsigned SK256  = (ROWS/16) * (256 >> 5);   // 151*8 = 1208 blocks
    const unsigned SK32_1024 = ((ROWS+31)/32) * (1024 >> 5);  // 76*32 = 2432
    const unsigned SK32_768  = ((ROWS+31)/32) * (768  >> 5);  // 76*24 = 1824
    const unsigned SQKG  = (16*8*100 + 3) / 4;        // 3200 blocks

    // ---- build_x + all weight packs, one dispatch ----
    buildpack_kernel<<<ROWS + PACK_BLOCKS, blk, 0, stream>>>(
        spectra, latent, int_w, pe, x, xb, xqb, masses, maskf,
        in_w, inw_p, out_w, owt2, l1_w, l1w_p, l2_w, l2w_p, pe_p);

    // merged: PEK|PEV GEMM + L0 QKV projection (independent)
    pekv_qkv0_kernel<<<PEKV_BLK + QKV0_BLK, blk, 0, stream>>>(
        pe_p, inw_p + 256*DD, pekv, xqb, xb, inw_p, in_b, qb, kvb);

    // ---------------- layer 0 ----------------
    gemm_sqk<256,512><<<SQKG, blk, 0, stream>>>(qb, kvb, sqkb);
    attn_kernel<true,256,512><<<ROWS, blk, 0, stream>>>(
        qb, kvb + 256, pekv, sqkb, masses, maskf,
        owt2, out_b, x, n1_g, n1_b, x, xb);
    gemm_skinny32<256,__hip_bfloat16,1><<<SK32_1024, blk, 0, stream>>>(
        xb, l1w_p, l1_b, f1b, ROWS, 1024, 1024);
    gemm_skinny<1024><<<SK256, blk, 0, stream>>>(
        f1b, l2w_p, l2_b, y2, ROWS, 256, 256);
    add_ln_kernel<true><<<ROWS, blk, 0, stream>>>(x, y2, n2_g, n2_b, x, xb);

    // ---------------- layer 1 ----------------
    gemm_skinny32<256,__hip_bfloat16,0><<<SK32_768, blk, 0, stream>>>(
        xb, inw_p + 768*DD, in_b + 768, kvb, ROWS, 768, 768);
    gemm_sqk<768,768><<<SQKG, blk, 0, stream>>>(kvb, kvb + 256, sqkb);
    attn_kernel<false,768,768><<<ROWS, blk, 0, stream>>>(
        kvb, kvb + 512, nullptr, sqkb, masses, maskf,
        owt2 + (size_t)128*256, out_b + 256, x, n1_g + 256, n1_b + 256, x, xb);
    gemm_skinny32<256,__hip_bfloat16,1><<<SK32_1024, blk, 0, stream>>>(
        xb, l1w_p + FFN_*DD, l1_b + 1024, f1b, ROWS, 1024, 1024);
    gemm_skinny<1024><<<SK256, blk, 0, stream>>>(
        f1b, l2w_p + DD*FFN_, l2_b + 256, y2, ROWS, 256, 256);
    add_ln_kernel<false><<<ROWS, blk, 0, stream>>>(x, y2, n2_g + 256, n2_b + 256,
                                                   (float*)d_out, nullptr);
}

// Round 13
// 296.791 us; speedup vs baseline: 1.2270x; 1.0028x over previous
//
#include <hip/hip_runtime.h>
#include <hip/hip_bf16.h>
#include <math.h>

// Problem constants
#define BB 16
#define NP 150
#define NN 151          // N = Np + 1
#define DD 256
#define HH 8
#define HD 32
#define FFN_ 1024
#define PE_LEN 20200
#define ROWS (BB*NN)    // 2416
#define MPAD 2432       // ROWS padded to 32
#define PE_PAD 20224    // PE_LEN padded to 32
#define SQS 160         // Sqk padded row (151->160)

// r21: score distribution (302.8us). r23: fused attn+outproj+LN with
// transposed out_w (302.8us). r24: gemm_skinny32 for the wide GEMMs
// (297.6us, best). r25: attn epilogue issued 128 SCALAR dword loads per
// thread (outwT k2-stride 1KB) — 1/3 of the kernel's issue slots. Repack
// out_w into k2-QUADS: owt4[k8][gc][q] (q = k2&3) so the epilogue loads
// one u32x4 per 4 k2-steps: 32 VMEM instr (1KB/wave-instr, coalesced).
// Accumulator grouping & f32 order BIT-IDENTICAL to r24; same buffer size.
// Index semantics: pe0 idx = 10100; rel-bucket clips -> 100 / 20100.

typedef __attribute__((ext_vector_type(8))) short short8;   // 8 bf16 = 4 VGPR
typedef __attribute__((ext_vector_type(4))) float f32x4;
typedef __attribute__((ext_vector_type(4))) unsigned u32x4; // 4 dwords

#if defined(__has_builtin)
#if __has_builtin(__builtin_amdgcn_fdot2_f32_bf16)
#define HAVE_DOT2 1
#endif
#endif
#ifndef HAVE_DOT2
#define HAVE_DOT2 0
#endif

__device__ __forceinline__ float r16(float x) {
    return __bfloat162float(__float2bfloat16(x));   // RNE bf16 grid
}
__device__ __forceinline__ float us2f(unsigned short u) {
    return __uint_as_float((unsigned)u << 16);      // bf16 bits -> f32
}
__device__ __forceinline__ float lo2f(unsigned x) {
    return __uint_as_float(x << 16);                // low bf16 of dword
}
__device__ __forceinline__ float hi2f(unsigned x) {
    return __uint_as_float(x & 0xFFFF0000u);        // high bf16 of dword
}
__device__ __forceinline__ unsigned short f2us(float x) {
    __hip_bfloat16 h = __float2bfloat16(x);
    return *reinterpret_cast<unsigned short*>(&h);  // RNE bf16 bits
}
__device__ __forceinline__ unsigned cvtpk(float lo, float hi) {
    unsigned r;                                     // D.lo=bf16(lo) D.hi=bf16(hi), RNE
    asm("v_cvt_pk_bf16_f32 %0, %1, %2" : "=v"(r) : "v"(lo), "v"(hi));
    return r;
}
#if HAVE_DOT2
typedef __attribute__((ext_vector_type(2))) __bf16 bf16x2;
__device__ __forceinline__ float dot2bf(unsigned a, unsigned b, float acc) {
    bf16x2 av = __builtin_bit_cast(bf16x2, a);
    bf16x2 bv = __builtin_bit_cast(bf16x2, b);
    return __builtin_amdgcn_fdot2_f32_bf16(av, bv, acc, false);
}
#endif

// ---------------------------------------------------------------------------
// build_x (+ fused weight packs on trailing blocks).
// owt4: out_w transposed k2-quad pack: owt4[l*32768 + k8*1024 + gc*4 + q]
//       = bf16(W[gc][2*(4k8+q)]) | bf16(W[gc][2*(4k8+q)+1])<<16.
// ---------------------------------------------------------------------------
#define PACK_BLOCKS 1024
__global__ __launch_bounds__(256) void buildpack_kernel(
    const float* __restrict__ spectra, const float* __restrict__ latent,
    const float* __restrict__ int_w, const float* __restrict__ pe,
    float* __restrict__ x, __hip_bfloat16* __restrict__ xb,
    __hip_bfloat16* __restrict__ xqb,
    float* __restrict__ masses, float* __restrict__ maskf,
    const float* __restrict__ in_w,  __hip_bfloat16* __restrict__ inw_p,
    const float* __restrict__ out_w, unsigned* __restrict__ owt4,
    const float* __restrict__ l1_w,  __hip_bfloat16* __restrict__ l1w_p,
    const float* __restrict__ l2_w,  __hip_bfloat16* __restrict__ l2w_p,
    __hip_bfloat16* __restrict__ pe_p)
{
    int tid = threadIdx.x;
    if (blockIdx.x < ROWS) {
        int bn = blockIdx.x;            // b*NN + n
        int b = bn / NN, n = bn % NN;
        float val;
        if (n == 0) {
            val = latent[tid];
            if (tid == 0) { masses[bn] = 0.0f; maskf[bn] = 0.0f; }
        } else {
            float mz = spectra[(b*NP + n - 1)*2 + 0];
            float it = spectra[(b*NP + n - 1)*2 + 1];
            int i = (tid < 128) ? tid : tid - 128;
            const double base_d = 0.001 / (2.0 * 3.141592653589793);
            double term_d = base_d * pow(1.0e7, (double)i / 127.0);
            float tf = (float)term_d;                   // .astype(np.float32)
            double arg = (double)mz / (double)tf;
            double sv = (tid < 128) ? sin(arg) : cos(arg);
            val = (float)sv + it * int_w[tid];
            if (tid == 0) {
                masses[bn] = mz;
                maskf[bn] = ((mz + it) == 0.0f) ? 1.0f : 0.0f;
            }
        }
        x[bn*DD + tid] = val;
        xb[bn*DD + tid] = __float2bfloat16(val);
        xqb[bn*DD + tid] = __float2bfloat16(val + pe[10100*DD + tid]);
    } else {
        long long base = (long long)(blockIdx.x - ROWS) * 256 + tid;
        const long long stride = (long long)PACK_BLOCKS * 256;
        for (long long i = base; i < (long long)PE_PAD*DD; i += stride)
            pe_p[i] = __float2bfloat16(i < (long long)PE_LEN*DD ? pe[i] : 0.0f);
        for (long long i = base; i < 2LL*768*DD; i += stride)
            inw_p[i] = __float2bfloat16(in_w[i]);
        for (long long i = base; i < 2LL*32768; i += stride) {
            long long l = i / 32768, rem = i % 32768;
            long long k8 = rem / 1024, rem2 = rem % 1024;
            long long gc = rem2 / 4, q = rem2 % 4;
            long long k2 = k8*4 + q;
            const float* src = out_w + l*DD*DD + gc*DD + 2*k2;
            owt4[i] = (unsigned)f2us(src[0]) | ((unsigned)f2us(src[1]) << 16);
        }
        for (long long i = base; i < 2LL*FFN_*DD; i += stride)
            l1w_p[i] = __float2bfloat16(l1_w[i]);
        for (long long i = base; i < 2LL*DD*FFN_; i += stride)
            l2w_p[i] = __float2bfloat16(l2_w[i]);
    }
}

// ---------------------------------------------------------------------------
// Skinny32 GEMM (wide-Nc ROWS GEMMs): one 32x32 tile per BLOCK, K split
// across the 4 waves (chain 8->2 for K=256), LDS partial reduce
// red[4][16][65], distributed epilogue r16(r16(sum)+r16(bias)) [+relu].
// ---------------------------------------------------------------------------
template<int K, typename CT, int RELU>
__global__ __launch_bounds__(256) void gemm_skinny32(
    const __hip_bfloat16* __restrict__ A, const __hip_bfloat16* __restrict__ W,
    const float* __restrict__ bias, CT* __restrict__ C,
    int M, int Nc, int ldc)
{
    int NT = Nc >> 5;
    int mt = blockIdx.x / NT, nt = blockIdx.x % NT;
    int m0 = mt * 32, n0 = nt * 32;
    int wave = threadIdx.x >> 6;
    int lane = threadIdx.x & 63;
    int rl = lane & 15, q8 = (lane >> 4) * 8;
    const int K4 = K >> 2;              // K slice per wave
    int k0 = wave * K4;

    const short8* Ap0 = (const short8*)(A + (size_t)(m0 + rl)*K + k0 + q8);
    const short8* Ap1 = (const short8*)(A + (size_t)(m0 + 16 + rl)*K + k0 + q8);
    const short8* Wp0 = (const short8*)(W + (size_t)(n0 + rl)*K + k0 + q8);
    const short8* Wp1 = (const short8*)(W + (size_t)(n0 + 16 + rl)*K + k0 + q8);

    f32x4 acc00 = {0,0,0,0}, acc01 = {0,0,0,0};
    f32x4 acc10 = {0,0,0,0}, acc11 = {0,0,0,0};
    #pragma unroll
    for (int s = 0; s < K4/32; ++s) {
        short8 a0 = Ap0[s*4];
        short8 a1 = Ap1[s*4];
        short8 b0 = Wp0[s*4];
        short8 b1 = Wp1[s*4];
        acc00 = __builtin_amdgcn_mfma_f32_16x16x32_bf16(a0, b0, acc00, 0, 0, 0);
        acc01 = __builtin_amdgcn_mfma_f32_16x16x32_bf16(a0, b1, acc01, 0, 0, 0);
        acc10 = __builtin_amdgcn_mfma_f32_16x16x32_bf16(a1, b0, acc10, 0, 0, 0);
        acc11 = __builtin_amdgcn_mfma_f32_16x16x32_bf16(a1, b1, acc11, 0, 0, 0);
    }

    // slots: sl = sm*8 + sn*4 + rg  (sm,sn in {0,1}, rg in 0..3)
    __shared__ float red[4][16][65];
    #pragma unroll
    for (int rg = 0; rg < 4; ++rg) {
        red[wave][0*8 + 0*4 + rg][lane] = acc00[rg];
        red[wave][0*8 + 1*4 + rg][lane] = acc01[rg];
        red[wave][1*8 + 0*4 + rg][lane] = acc10[rg];
        red[wave][1*8 + 1*4 + rg][lane] = acc11[rg];
    }
    __syncthreads();

    #pragma unroll
    for (int t = 0; t < 4; ++t) {
        int sl = wave*4 + t;
        float s = red[0][sl][lane] + red[1][sl][lane]
                + red[2][sl][lane] + red[3][sl][lane];
        int rg = sl & 3, sn = (sl >> 2) & 1, sm = sl >> 3;
        int gr = m0 + sm*16 + (lane >> 4)*4 + rg;
        int gc = n0 + sn*16 + rl;
        float val = r16(s);
        val = r16(val + r16(bias[gc]));
        if (RELU) val = fmaxf(val, 0.0f);
        if (gr < M) C[(size_t)gr*ldc + gc] = (CT)val;
    }
}

// ---------------------------------------------------------------------------
// Skinny GEMM for Nc=256 (FFN-down): one 16x32 tile per BLOCK, K split
// across the 4 waves, LDS partial reduce, distributed epilogue.
// ---------------------------------------------------------------------------
template<int K>
__global__ __launch_bounds__(256) void gemm_skinny(
    const __hip_bfloat16* __restrict__ A, const __hip_bfloat16* __restrict__ W,
    const float* __restrict__ bias, float* __restrict__ C,
    int M, int Nc, int ldc)
{
    int NT = Nc >> 5;
    int id = blockIdx.x;
    int mt = id / NT, nt = id % NT;
    int m0 = mt * 16, n0 = nt * 32;
    int wave = threadIdx.x >> 6;
    int lane = threadIdx.x & 63;
    int rl = lane & 15, q8 = (lane >> 4) * 8;
    const int K4 = K >> 2;              // K slice per wave
    int k0 = wave * K4;

    const short8* Ap  = (const short8*)(A + (size_t)(m0 + rl)*K + k0 + q8);
    const short8* Wp0 = (const short8*)(W + (size_t)(n0 + rl)*K + k0 + q8);
    const short8* Wp1 = (const short8*)(W + (size_t)(n0 + 16 + rl)*K + k0 + q8);

    f32x4 acc0 = {0,0,0,0}, acc1 = {0,0,0,0};
    #pragma unroll
    for (int s = 0; s < K4/32; ++s) {
        short8 a  = Ap[s*4];
        short8 b0 = Wp0[s*4];
        short8 b1 = Wp1[s*4];
        acc0 = __builtin_amdgcn_mfma_f32_16x16x32_bf16(a, b0, acc0, 0, 0, 0);
        acc1 = __builtin_amdgcn_mfma_f32_16x16x32_bf16(a, b1, acc1, 0, 0, 0);
    }

    __shared__ float red[4][8][65];     // [wave][slot][lane] pad->no conflicts
    #pragma unroll
    for (int rg = 0; rg < 4; ++rg) {
        red[wave][rg][lane]   = acc0[rg];
        red[wave][4+rg][lane] = acc1[rg];
    }
    __syncthreads();

    #pragma unroll
    for (int t = 0; t < 2; ++t) {
        int sl = wave*2 + t;
        float s = red[0][sl][lane] + red[1][sl][lane]
                + red[2][sl][lane] + red[3][sl][lane];
        int rg = sl & 3, sn = sl >> 2;
        int gr = m0 + (lane >> 4)*4 + rg;
        int gc = n0 + sn*16 + rl;
        float val = r16(s);
        val = r16(val + r16(bias[gc]));
        if (gr < M) C[(size_t)gr*ldc + gc] = val;
    }
}

// ---------------------------------------------------------------------------
// Batched score GEMM: Sqk[b][h][i][j] = sum_d Q[b,i,h*32+d] * K[b,j,h*32+d],
// f32, unscaled, unmasked. One 16x16 (i x j) tile per wave, K=32 = 1 MFMA.
// ---------------------------------------------------------------------------
template<int QS, int KS>
__global__ __launch_bounds__(256) void gemm_sqk(
    const __hip_bfloat16* __restrict__ Q, const __hip_bfloat16* __restrict__ Kp,
    float* __restrict__ S)
{
    int wave = threadIdx.x >> 6;
    int lane = threadIdx.x & 63;
    int id = blockIdx.x * 4 + wave;         // b(16) x h(8) x it(10) x jt(10)
    if (id >= 16*8*100) return;
    int jt = id % 10, it = (id / 10) % 10;
    int h = (id / 100) & 7, b = id / 800;
    int i0 = it * 16, j0 = jt * 16;
    int rl = lane & 15, q8 = (lane >> 4) * 8;

    short8 a  = *(const short8*)(Q  + (size_t)(b*NN + i0 + rl)*QS + h*32 + q8);
    short8 kb = *(const short8*)(Kp + (size_t)(b*NN + j0 + rl)*KS + h*32 + q8);
    f32x4 acc = {0,0,0,0};
    acc = __builtin_amdgcn_mfma_f32_16x16x32_bf16(a, kb, acc, 0, 0, 0);

    float* Sb = S + ((size_t)(b*8 + h))*SQS*SQS;
    int rbase = (lane >> 4) * 4;
    #pragma unroll
    for (int rg = 0; rg < 4; ++rg) {
        int ii = i0 + rbase + rg, jj = j0 + rl;
        if (ii < NN && jj < NN)
            Sb[(size_t)ii*SQS + jj] = acc[rg];
    }
}

// ---------------------------------------------------------------------------
// Merged pekv GEMM + L0 QKV projection (independent, both read weight packs).
// ---------------------------------------------------------------------------
#define PEKV_BLK 632u   // ceil(158*16 tiles / 4 waves)
#define QKV0_BLK 456u   // ceil(76*24 tiles / 4 waves)

__device__ __forceinline__ void pekv_body(
    unsigned bid, int wave, int lane,
    const __hip_bfloat16* __restrict__ A, const __hip_bfloat16* __restrict__ W,
    __hip_bfloat16* __restrict__ C)
{
    const int K = 256, Nc = 512, ldc = 512, M = PE_LEN;
    int NT = Nc >> 5;
    int MT4 = (M + 127) >> 7;
    int id = bid * 4 + wave;
    if (id >= MT4 * NT) return;
    int mt = id / NT, nt = id % NT;
    int m0 = mt * 128, n0 = nt * 32;
    int rl = lane & 15, q8 = (lane >> 4) * 8;

    const short8* Ab  = (const short8*)(A + (size_t)(m0 + rl)*K + q8);
    const short8* Wp0 = (const short8*)(W + (size_t)(n0 + rl)*K + q8);
    const short8* Wp1 = (const short8*)(W + (size_t)(n0 + 16 + rl)*K + q8);
    const int rstep = K >> 3;                  // short8 units per row

    f32x4 acc[4][2][2] = {};
    for (int s = 0; s < 8; ++s) {              // K/32 = 8
        short8 b0 = Wp0[s*4];
        short8 b1 = Wp1[s*4];
        short8 a[4][2];
        #pragma unroll
        for (int t = 0; t < 4; ++t) {
            a[t][0] = Ab[(size_t)(t*32)*rstep + s*4];
            a[t][1] = Ab[(size_t)(t*32+16)*rstep + s*4];
        }
        #pragma unroll
        for (int t = 0; t < 4; ++t) {
            acc[t][0][0] = __builtin_amdgcn_mfma_f32_16x16x32_bf16(a[t][0], b0, acc[t][0][0], 0, 0, 0);
            acc[t][0][1] = __builtin_amdgcn_mfma_f32_16x16x32_bf16(a[t][0], b1, acc[t][0][1], 0, 0, 0);
            acc[t][1][0] = __builtin_amdgcn_mfma_f32_16x16x32_bf16(a[t][1], b0, acc[t][1][0], 0, 0, 0);
            acc[t][1][1] = __builtin_amdgcn_mfma_f32_16x16x32_bf16(a[t][1], b1, acc[t][1][1], 0, 0, 0);
        }
    }

    int rbase = (lane >> 4) * 4;
    #pragma unroll
    for (int t = 0; t < 4; ++t) {
        #pragma unroll
        for (int sm = 0; sm < 2; ++sm) {
            #pragma unroll
            for (int sn = 0; sn < 2; ++sn) {
                f32x4 a = acc[t][sm][sn];
                int gc = n0 + sn*16 + rl;
                #pragma unroll
                for (int rg = 0; rg < 4; ++rg) {
                    int gr = m0 + t*32 + sm*16 + rbase + rg;
                    if (gr < M)
                        C[(size_t)gr*ldc + gc] = (__hip_bfloat16)r16(a[rg]);
                }
            }
        }
    }
}

__device__ __forceinline__ void qkv0_body(
    unsigned bid, int wave, int lane,
    const __hip_bfloat16* __restrict__ xqb, const __hip_bfloat16* __restrict__ xb,
    const __hip_bfloat16* __restrict__ inw_p, const float* __restrict__ in_b,
    __hip_bfloat16* __restrict__ qb, __hip_bfloat16* __restrict__ kvb, int M)
{
    int MT = (M + 31) >> 5;
    int id = bid * 4 + wave;
    if (id >= MT * 24) return;
    int mt = id / 24, ntt = id % 24;
    bool isQ = (ntt < 8);
    const __hip_bfloat16* A = isQ ? xqb : xb;
    const __hip_bfloat16* W = inw_p + (isQ ? (size_t)ntt*32*DD
                                           : (size_t)(256 + (ntt-8)*32)*DD);
    const float* bias = in_b + (isQ ? ntt*32 : 256 + (ntt-8)*32);
    __hip_bfloat16* C = isQ ? qb : kvb;
    int ldc = isQ ? 256 : 512;
    int cbase = isQ ? ntt*32 : (ntt-8)*32;
    int m0 = mt * 32;
    int rl = lane & 15, q8 = (lane >> 4) * 8;
    const int K = DD;

    const short8* Ap0 = (const short8*)(A + (size_t)(m0 + rl)*K + q8);
    const short8* Ap1 = (const short8*)(A + (size_t)(m0 + 16 + rl)*K + q8);
    const short8* Wp0 = (const short8*)(W + (size_t)(rl)*K + q8);
    const short8* Wp1 = (const short8*)(W + (size_t)(16 + rl)*K + q8);

    f32x4 acc00 = {0,0,0,0}, acc01 = {0,0,0,0};
    f32x4 acc10 = {0,0,0,0}, acc11 = {0,0,0,0};
    for (int s = 0; s < K/32; ++s) {
        short8 a0 = Ap0[s*4];
        short8 a1 = Ap1[s*4];
        short8 b0 = Wp0[s*4];
        short8 b1 = Wp1[s*4];
        acc00 = __builtin_amdgcn_mfma_f32_16x16x32_bf16(a0, b0, acc00, 0, 0, 0);
        acc01 = __builtin_amdgcn_mfma_f32_16x16x32_bf16(a0, b1, acc01, 0, 0, 0);
        acc10 = __builtin_amdgcn_mfma_f32_16x16x32_bf16(a1, b0, acc10, 0, 0, 0);
        acc11 = __builtin_amdgcn_mfma_f32_16x16x32_bf16(a1, b1, acc11, 0, 0, 0);
    }

    int rbase = (lane >> 4) * 4;
    #pragma unroll
    for (int sm = 0; sm < 2; ++sm) {
        #pragma unroll
        for (int sn = 0; sn < 2; ++sn) {
            f32x4 a = (sm == 0) ? (sn == 0 ? acc00 : acc01)
                                : (sn == 0 ? acc10 : acc11);
            int gc = cbase + sn*16 + rl;
            float bv = r16(bias[sn*16 + rl]);
            #pragma unroll
            for (int rg = 0; rg < 4; ++rg) {
                int gr = m0 + sm*16 + rbase + rg;
                if (gr < M) {
                    float val = r16(a[rg]);
                    val = r16(val + bv);
                    C[(size_t)gr*ldc + gc] = (__hip_bfloat16)val;
                }
            }
        }
    }
}

__global__ __launch_bounds__(256) void pekv_qkv0_kernel(
    const __hip_bfloat16* __restrict__ pe_p, const __hip_bfloat16* __restrict__ wkv0,
    __hip_bfloat16* __restrict__ pekv,
    const __hip_bfloat16* __restrict__ xqb, const __hip_bfloat16* __restrict__ xb,
    const __hip_bfloat16* __restrict__ inw_p, const float* __restrict__ in_b,
    __hip_bfloat16* __restrict__ qb, __hip_bfloat16* __restrict__ kvb)
{
    int wave = threadIdx.x >> 6;
    int lane = threadIdx.x & 63;
    if (blockIdx.x < PEKV_BLK)
        pekv_body(blockIdx.x, wave, lane, pe_p, wkv0, pekv);
    else
        qkv0_body(blockIdx.x - PEKV_BLK, wave, lane, xqb, xb, inw_p, in_b,
                  qb, kvb, ROWS);
}

// ---------------------------------------------------------------------------
// Fused attention + out-proj + residual + layernorm. One block per (b,i),
// b = blk&15 (XCD locality). Thread (g = tid>>5, c = tid&31).
// Scores: Sqk preload; USE_PE adds PE-gather dot (Phase A). Phase B as r21.
// Epilogue: y row -> bf16 pairs (ypk, LDS broadcast) -> per-thread 256-dot
// vs k2-QUAD-packed out_w (owt4: u32x4 per 4 k2, coalesced) ->
// r16(r16(dot)+r16(bias)) -> residual -> LN -> xout/xbout.
// ---------------------------------------------------------------------------
template<bool USE_PE, int QS, int VS>
__global__ __launch_bounds__(256) void attn_kernel(
    const __hip_bfloat16* __restrict__ qp,
    const __hip_bfloat16* __restrict__ vp,
    const __hip_bfloat16* __restrict__ pekv,
    const float* __restrict__ sqk,
    const float* __restrict__ masses, const float* __restrict__ maskf,
    const unsigned* __restrict__ outwT4, const float* __restrict__ outb,
    const float* __restrict__ xres,
    const float* __restrict__ lng, const float* __restrict__ lnb,
    float* __restrict__ xout, __hip_bfloat16* __restrict__ xbout)
{
    int b = blockIdx.x & 15;        // XCD-locality swizzle (pure permutation)
    int i = blockIdx.x >> 4;
    int tid = threadIdx.x;
    int c = tid & 31;               // 8-column chunk index
    int g = tid >> 5;               // row-residue class
    int h = c >> 2;                 // head owning columns c*8..c*8+7
    const float scale = 0.17677669529663687f;   // 1/sqrt(32)

    __shared__ float sc[HH][152];
    __shared__ float msh[152];
    __shared__ int   tj[152];
    __shared__ __align__(16) float part[8][264];
    __shared__ float yrow[256];
    __shared__ unsigned ypk[128];
    __shared__ float red2[4];

    if (tid < NN) {
        float mval = maskf[b*NN + tid];
        msh[tid] = mval;
        if (USE_PE) {
            double m = (double)masses[b*NN + tid] - (double)masses[b*NN + i];
            m = fmin(fmax(m, -100.0), 100.0);
            tj[tid] = (int)(((m + 1.0) + 100.0) / 0.01);  // f64: clips 100/20100
        }
        // preload Sqk rows (coalesced in j)
        const float* Sb = sqk + ((size_t)(b*8))*SQS*SQS + (size_t)i*SQS + tid;
        if (USE_PE) {
            #pragma unroll
            for (int hh = 0; hh < 8; ++hh)
                sc[hh][tid] = Sb[(size_t)hh*SQS*SQS];     // raw; PE+scale+mask in Phase A
        } else {
            #pragma unroll
            for (int hh = 0; hh < 8; ++hh) {
                float s = Sb[(size_t)hh*SQS*SQS] * scale;
                sc[hh][tid] = (mval != 0.0f) ? -1e9f : s;
            }
        }
    }

    // preload Q chunk (only needed for the PE dot)
    unsigned qw[4];
#if !HAVE_DOT2
    float qf[8];
#endif
    if (USE_PE) {
        const u32x4 q4 = *(const u32x4*)((const unsigned short*)qp
                            + (size_t)(b*NN + i)*QS + c*8);
        qw[0] = q4[0]; qw[1] = q4[1]; qw[2] = q4[2]; qw[3] = q4[3];
#if !HAVE_DOT2
        #pragma unroll
        for (int w = 0; w < 4; ++w) { qf[2*w] = lo2f(qw[w]); qf[2*w+1] = hi2f(qw[w]); }
#endif
    }
    __syncthreads();

    const unsigned short* vbase = (const unsigned short*)vp + (size_t)(b*NN)*VS + c*8;
    const unsigned short* pkb = (const unsigned short*)pekv + c*8;        // PEK col
    const unsigned short* pvb = (const unsigned short*)pekv + 256 + c*8;  // PEV col

    // ---- Phase A (USE_PE only): PE-gather dot added to preloaded Sqk ----
    if (USE_PE) {
        int j = g;
        u32x4 pcur = *(const u32x4*)(pkb + (size_t)tj[j]*512);
        for (int p = 0; p < 19; ++p) {
            int jn = j + 8;
            bool more = (jn < NN);
            u32x4 pn;
            if (more) pn = *(const u32x4*)(pkb + (size_t)tj[jn]*512);
            float acc = 0.0f;
#if HAVE_DOT2
            #pragma unroll
            for (int w = 0; w < 4; ++w) acc = dot2bf(qw[w], pcur[w], acc);
#else
            #pragma unroll
            for (int w = 0; w < 4; ++w) {
                acc = fmaf(qf[2*w],   lo2f(pcur[w]), acc);
                acc = fmaf(qf[2*w+1], hi2f(pcur[w]), acc);
            }
#endif
            acc += __shfl_xor(acc, 1);
            acc += __shfl_xor(acc, 2);
            if ((c & 3) == 0) {
                float s = (sc[h][j] + acc) * scale;
                if (msh[j] != 0.0f) s = -1e9f;
                sc[h][j] = s;
            }
            if (!more) break;
            j = jn; pcur = pn;
        }
        __syncthreads();
    }

    // ---- softmax per head, f32, within 32-lane group (head = g) ----
    {
        int lane = tid & 31;
        int hh = g;
        float mx = -INFINITY;
        for (int j = lane; j < NN; j += 32) mx = fmaxf(mx, sc[hh][j]);
        #pragma unroll
        for (int off = 16; off; off >>= 1) mx = fmaxf(mx, __shfl_xor(mx, off, 32));
        float sum = 0.0f;
        for (int j = lane; j < NN; j += 32) {
            float e = expf(sc[hh][j] - mx);
            sc[hh][j] = e;
            sum += e;
        }
        #pragma unroll
        for (int off = 16; off; off >>= 1) sum += __shfl_xor(sum, off, 32);
        float inv = 1.0f / sum;
        for (int j = lane; j < NN; j += 32) sc[hh][j] = r16(sc[hh][j] * inv); // bf16(a)
    }
    __syncthreads();

    // ---- Phase B: partial y over row class, then cross-group reduce ----
    {
        float ya[8];
        #pragma unroll
        for (int u = 0; u < 8; ++u) ya[u] = 0.0f;

#if HAVE_DOT2
        // rows paired (jA = g+16t, jB = jA+8), t = 0..8; tail row g+144 if valid
        u32x4 vA = *(const u32x4*)(vbase + (size_t)g*VS);
        u32x4 vB = *(const u32x4*)(vbase + (size_t)(g+8)*VS);
        u32x4 pA, pB;
        if (USE_PE) {
            pA = *(const u32x4*)(pvb + (size_t)tj[g]*512);
            pB = *(const u32x4*)(pvb + (size_t)tj[g+8]*512);
        }
        for (int t = 0; t < 9; ++t) {
            int jA = g + t*16, jB = jA + 8;
            u32x4 nvA, nvB, npA, npB;
            if (t < 8) {
                int nA = jA + 16, nB = jB + 16;
                nvA = *(const u32x4*)(vbase + (size_t)nA*VS);
                nvB = *(const u32x4*)(vbase + (size_t)nB*VS);
                if (USE_PE) {
                    npA = *(const u32x4*)(pvb + (size_t)tj[nA]*512);
                    npB = *(const u32x4*)(pvb + (size_t)tj[nB]*512);
                }
            }
            unsigned apair = cvtpk(sc[h][jA], sc[h][jB]);   // lo=aA hi=aB
            #pragma unroll
            for (int w = 0; w < 4; ++w) {
                unsigned lopair, hipair;
                if (USE_PE) {
                    float sA0 = lo2f(vA[w]) + lo2f(pA[w]);
                    float sA1 = hi2f(vA[w]) + hi2f(pA[w]);
                    float sB0 = lo2f(vB[w]) + lo2f(pB[w]);
                    float sB1 = hi2f(vB[w]) + hi2f(pB[w]);
                    lopair = cvtpk(sA0, sB0);
                    hipair = cvtpk(sA1, sB1);
                } else {
                    lopair = __builtin_amdgcn_perm(vB[w], vA[w], 0x05040100u);
                    hipair = __builtin_amdgcn_perm(vB[w], vA[w], 0x07060302u);
                }
                ya[2*w]   = dot2bf(apair, lopair, ya[2*w]);
                ya[2*w+1] = dot2bf(apair, hipair, ya[2*w+1]);
            }
            if (t < 8) {
                vA = nvA; vB = nvB;
                if (USE_PE) { pA = npA; pB = npB; }
            }
        }
        if (g + 144 < NN) {                 // tail row (g < 7)
            int jT = g + 144;
            u32x4 v = *(const u32x4*)(vbase + (size_t)jT*VS);
            u32x4 pq;
            if (USE_PE) pq = *(const u32x4*)(pvb + (size_t)tj[jT]*512);
            float aT = sc[h][jT];
            #pragma unroll
            for (int w = 0; w < 4; ++w) {
                float v0 = lo2f(v[w]), v1 = hi2f(v[w]);
                if (USE_PE) {
                    unsigned pk2 = cvtpk(v0 + lo2f(pq[w]), v1 + hi2f(pq[w]));
                    v0 = lo2f(pk2); v1 = hi2f(pk2);
                }
                ya[2*w]   = fmaf(aT, v0, ya[2*w]);
                ya[2*w+1] = fmaf(aT, v1, ya[2*w+1]);
            }
        }
#else
        int j = g;
        u32x4 vcur = *(const u32x4*)(vbase + (size_t)j*VS);
        u32x4 pcur;
        if (USE_PE) pcur = *(const u32x4*)(pvb + (size_t)tj[j]*512);
        float acur = sc[h][j];
        for (int p = 0; p < 19; ++p) {
            int jn = j + 8;
            bool more = (jn < NN);
            u32x4 vn, pn;
            float an = 0.0f;
            if (more) {
                vn = *(const u32x4*)(vbase + (size_t)jn*VS);
                if (USE_PE) pn = *(const u32x4*)(pvb + (size_t)tj[jn]*512);
                an = sc[h][jn];
            }
            #pragma unroll
            for (int w = 0; w < 4; ++w) {
                float v0 = lo2f(vcur[w]), v1 = hi2f(vcur[w]);
                if (USE_PE) {
                    v0 = r16(v0 + lo2f(pcur[w]));
                    v1 = r16(v1 + hi2f(pcur[w]));
                }
                ya[2*w]   = fmaf(acur, v0, ya[2*w]);
                ya[2*w+1] = fmaf(acur, v1, ya[2*w+1]);
            }
            if (!more) break;
            j = jn; vcur = vn; acur = an;
            if (USE_PE) pcur = pn;
        }
#endif
        f32x4* pp = (f32x4*)&part[g][c*8];
        pp[0] = f32x4{ya[0], ya[1], ya[2], ya[3]};
        pp[1] = f32x4{ya[4], ya[5], ya[6], ya[7]};
    }
    __syncthreads();

    // ---- fused out-proj + residual + layernorm (row-local) ----
    {
        float s = part[0][tid];
        #pragma unroll
        for (int g2 = 1; g2 < 8; ++g2) s += part[g2][tid];
        yrow[tid] = s;
    }
    __syncthreads();
    if (tid < 128) ypk[tid] = cvtpk(yrow[2*tid], yrow[2*tid + 1]);  // bf16 y operand
    __syncthreads();
    {
        const u32x4* Wq = (const u32x4*)outwT4;     // [k8][gc] quads
        float a0 = 0.0f, a1 = 0.0f, a2 = 0.0f, a3 = 0.0f;
        #pragma unroll
        for (int k8 = 0; k8 < 32; ++k8) {
            u32x4 w = Wq[(size_t)k8*256 + tid];
            int k2 = k8*4;
#if HAVE_DOT2
            a0 = dot2bf(ypk[k2+0], w[0], a0);
            a1 = dot2bf(ypk[k2+1], w[1], a1);
            a2 = dot2bf(ypk[k2+2], w[2], a2);
            a3 = dot2bf(ypk[k2+3], w[3], a3);
#else
            a0 = fmaf(lo2f(ypk[k2+0]), lo2f(w[0]), a0);
            a1 = fmaf(hi2f(ypk[k2+0]), hi2f(w[0]), a1);
            a2 = fmaf(lo2f(ypk[k2+1]), lo2f(w[1]), a2);
            a3 = fmaf(hi2f(ypk[k2+1]), hi2f(w[1]), a3);
            a0 = fmaf(lo2f(ypk[k2+2]), lo2f(w[2]), a0);
            a1 = fmaf(hi2f(ypk[k2+2]), hi2f(w[2]), a1);
            a2 = fmaf(lo2f(ypk[k2+3]), lo2f(w[3]), a2);
            a3 = fmaf(hi2f(ypk[k2+3]), hi2f(w[3]), a3);
#endif
        }
        float val = r16((a0 + a1) + (a2 + a3));
        val = r16(val + r16(outb[tid]));
        size_t row = (size_t)(b*NN + i)*DD + tid;
        float v = xres[row] + val;

        float sr = v;
        #pragma unroll
        for (int off = 32; off; off >>= 1) sr += __shfl_xor(sr, off);
        if ((tid & 63) == 0) red2[tid >> 6] = sr;
        __syncthreads();
        float mu = (red2[0] + red2[1] + red2[2] + red2[3]) * (1.0f/256.0f);
        __syncthreads();
        float dd = v - mu;
        float s2 = dd*dd;
        #pragma unroll
        for (int off = 32; off; off >>= 1) s2 += __shfl_xor(s2, off);
        if ((tid & 63) == 0) red2[tid >> 6] = s2;
        __syncthreads();
        float var = (red2[0] + red2[1] + red2[2] + red2[3]) * (1.0f/256.0f);
        float out = dd * (1.0f / sqrtf(var + 1e-5f)) * lng[tid] + lnb[tid];
        xout[row] = out;
        xbout[row] = __float2bfloat16(out);
    }
}

// ---------------------------------------------------------------------------
// add + layernorm, one block per row (f32). Optionally writes bf16 shadow.
// ---------------------------------------------------------------------------
template<bool WRITE_B>
__global__ __launch_bounds__(256) void add_ln_kernel(
    const float* __restrict__ xin, const float* __restrict__ res,
    const float* __restrict__ g, const float* __restrict__ bb,
    float* __restrict__ xout, __hip_bfloat16* __restrict__ xbout)
{
    int r = blockIdx.x; int tid = threadIdx.x;
    float v = xin[r*DD + tid] + res[r*DD + tid];
    __shared__ float red[4];
    float s = v;
    #pragma unroll
    for (int off = 32; off; off >>= 1) s += __shfl_xor(s, off);
    if ((tid & 63) == 0) red[tid >> 6] = s;
    __syncthreads();
    float mu = (red[0] + red[1] + red[2] + red[3]) * (1.0f/256.0f);
    __syncthreads();
    float d = v - mu;
    float s2 = d*d;
    #pragma unroll
    for (int off = 32; off; off >>= 1) s2 += __shfl_xor(s2, off);
    if ((tid & 63) == 0) red[tid >> 6] = s2;
    __syncthreads();
    float var = (red[0] + red[1] + red[2] + red[3]) * (1.0f/256.0f);
    float out = d * (1.0f / sqrtf(var + 1e-5f)) * g[tid] + bb[tid];
    xout[r*DD + tid] = out;
    if (WRITE_B) xbout[r*DD + tid] = __float2bfloat16(out);
}

// ---------------------------------------------------------------------------
extern "C" void kernel_launch(void* const* d_in, const int* in_sizes, int n_in,
                              void* d_out, int out_size, void* d_ws, size_t ws_size,
                              hipStream_t stream)
{
    const float* spectra = (const float*)d_in[0];
    const float* pe      = (const float*)d_in[1];
    const float* latent  = (const float*)d_in[2];
    const float* int_w   = (const float*)d_in[3];
    const float* in_w    = (const float*)d_in[4];
    const float* in_b    = (const float*)d_in[5];
    const float* out_w   = (const float*)d_in[6];
    const float* out_b   = (const float*)d_in[7];
    const float* l1_w    = (const float*)d_in[8];
    const float* l1_b    = (const float*)d_in[9];
    const float* l2_w    = (const float*)d_in[10];
    const float* l2_b    = (const float*)d_in[11];
    const float* n1_g    = (const float*)d_in[12];
    const float* n1_b    = (const float*)d_in[13];
    const float* n2_g    = (const float*)d_in[14];
    const float* n2_b    = (const float*)d_in[15];

    // ---- workspace layout ----
    float* x      = (float*)d_ws;                 // ROWS*256
    float* y2     = x      + ROWS*DD;             // ROWS*256
    float* masses = y2     + ROWS*DD;             // ROWS
    float* maskf  = masses + ROWS;                // ROWS
    float* sqkb   = maskf  + ROWS;                // 16*8*SQS*SQS f32 (13.1MB)
    __hip_bfloat16* bp = (__hip_bfloat16*)(sqkb + (size_t)16*8*SQS*SQS);
    __hip_bfloat16* xb    = bp;  bp += (size_t)MPAD*DD;
    __hip_bfloat16* xqb   = bp;  bp += (size_t)MPAD*DD;
    __hip_bfloat16* qb    = bp;  bp += (size_t)MPAD*DD;
    __hip_bfloat16* kvb   = bp;  bp += (size_t)MPAD*768;
    __hip_bfloat16* f1b   = bp;  bp += (size_t)MPAD*FFN_;
    __hip_bfloat16* pekv  = bp;  bp += (size_t)PE_PAD*512;
    __hip_bfloat16* pe_p  = bp;  bp += (size_t)PE_PAD*DD;
    __hip_bfloat16* inw_p = bp;  bp += (size_t)2*768*DD;
    unsigned* owt4 = (unsigned*)bp;  bp += (size_t)2*DD*DD;   // 2*32768 dwords
    __hip_bfloat16* l1w_p = bp;  bp += (size_t)2*FFN_*DD;
    __hip_bfloat16* l2w_p = bp;  bp += (size_t)2*DD*FFN_;

    dim3 blk(256);
    const unsigned SK256  = (ROWS/16) * (256 >> 5);   // 151*8 = 1208 blocks
    const unsigned SK32_1024 = ((ROWS+31)/32) * (1024 >> 5);  // 76*32 = 2432
    const unsigned SK32_768  = ((ROWS+31)/32) * (768  >> 5);  // 76*24 = 1824
    const unsigned SQKG  = (16*8*100 + 3) / 4;        // 3200 blocks

    // ---- build_x + all weight packs, one dispatch ----
    buildpack_kernel<<<ROWS + PACK_BLOCKS, blk, 0, stream>>>(
        spectra, latent, int_w, pe, x, xb, xqb, masses, maskf,
        in_w, inw_p, out_w, owt4, l1_w, l1w_p, l2_w, l2w_p, pe_p);

    // merged: PEK|PEV GEMM + L0 QKV projection (independent)
    pekv_qkv0_kernel<<<PEKV_BLK + QKV0_BLK, blk, 0, stream>>>(
        pe_p, inw_p + 256*DD, pekv, xqb, xb, inw_p, in_b, qb, kvb);

    // ---------------- layer 0 ----------------
    gemm_sqk<256,512><<<SQKG, blk, 0, stream>>>(qb, kvb, sqkb);
    attn_kernel<true,256,512><<<ROWS, blk, 0, stream>>>(
        qb, kvb + 256, pekv, sqkb, masses, maskf,
        owt4, out_b, x, n1_g, n1_b, x, xb);
    gemm_skinny32<256,__hip_bfloat16,1><<<SK32_1024, blk, 0, stream>>>(
        xb, l1w_p, l1_b, f1b, ROWS, 1024, 1024);
    gemm_skinny<1024><<<SK256, blk, 0, stream>>>(
        f1b, l2w_p, l2_b, y2, ROWS, 256, 256);
    add_ln_kernel<true><<<ROWS, blk, 0, stream>>>(x, y2, n2_g, n2_b, x, xb);

    // ---------------- layer 1 ----------------
    gemm_skinny32<256,__hip_bfloat16,0><<<SK32_768, blk, 0, stream>>>(
        xb, inw_p + 768*DD, in_b + 768, kvb, ROWS, 768, 768);
    gemm_sqk<768,768><<<SQKG, blk, 0, stream>>>(kvb, kvb + 256, sqkb);
    attn_kernel<false,768,768><<<ROWS, blk, 0, stream>>>(
        kvb, kvb + 512, nullptr, sqkb, masses, maskf,
        owt4 + (size_t)32768, out_b + 256, x, n1_g + 256, n1_b + 256, x, xb);
    gemm_skinny32<256,__hip_bfloat16,1><<<SK32_1024, blk, 0, stream>>>(
        xb, l1w_p + FFN_*DD, l1_b + 1024, f1b, ROWS, 1024, 1024);
    gemm_skinny<1024><<<SK256, blk, 0, stream>>>(
        f1b, l2w_p + DD*FFN_, l2_b + 256, y2, ROWS, 256, 256);
    add_ln_kernel<false><<<ROWS, blk, 0, stream>>>(x, y2, n2_g + 256, n2_b + 256,
                                                   (float*)d_out, nullptr);
}